// Round 4
// baseline (1377.299 us; speedup 1.0000x reference)
//
#include <hip/hip_runtime.h>
#include <stdint.h>

using bf16x8 = __attribute__((ext_vector_type(8))) __bf16;
using u16x8  = __attribute__((ext_vector_type(8))) unsigned short;
using f32x4  = __attribute__((ext_vector_type(4))) float;

#define DMODEL 512
#define DFF    2048
#define TT     2048
#define BB     2
#define NH     8
#define HD     64

__device__ __forceinline__ unsigned short f2b(float f) {
  union { float f; uint32_t u; } c; c.f = f;
  uint32_t u = c.u;
  uint32_t r = (u + 0x7FFFu + ((u >> 16) & 1u)) >> 16;
  return (unsigned short)r;
}
__device__ __forceinline__ float b2f(unsigned short s) {
  union { uint32_t u; float f; } c; c.u = ((uint32_t)s) << 16;
  return c.f;
}
__device__ __forceinline__ bf16x8 asbf(u16x8 x) { return __builtin_bit_cast(bf16x8, x); }

__device__ __forceinline__ f32x4 mfma16(bf16x8 a, bf16x8 b, f32x4 c) {
  return __builtin_amdgcn_mfma_f32_16x16x32_bf16(a, b, c, 0, 0, 0);
}

__device__ __forceinline__ void gload16(const void* g, void* l) {
  __builtin_amdgcn_global_load_lds((__attribute__((address_space(1))) void*)(g),
                                   (__attribute__((address_space(3))) void*)(l),
                                   16, 0, 0);
}

// quantize 8 bf16 P values (as u16) to 8 bytes, scale x24
__device__ __forceinline__ uint2 pack8(u16x8 pst) {
  uint32_t lo = 0, hi = 0;
  #pragma unroll
  for (int j = 0; j < 4; ++j) {
    int a = (int)(b2f(pst[j]) * 24.f + 0.5f);     a = a > 255 ? 255 : a;
    int c = (int)(b2f(pst[4 + j]) * 24.f + 0.5f); c = c > 255 ? 255 : c;
    lo |= (uint32_t)a << (8 * j);
    hi |= (uint32_t)c << (8 * j);
  }
  uint2 r; r.x = lo; r.y = hi; return r;
}

// ---------------- f32 -> bf16 convert (weights) ----------------
__global__ void k_f2b(const float* __restrict__ in, unsigned short* __restrict__ out, int n4) {
  int i = blockIdx.x * blockDim.x + threadIdx.x;
  if (i < n4) {
    float4 v = ((const float4*)in)[i];
    ushort4 o;
    o.x = f2b(v.x); o.y = f2b(v.y); o.z = f2b(v.z); o.w = f2b(v.w);
    ((ushort4*)out)[i] = o;
  }
}

// ---------------- embedding + positional ----------------
__global__ void k_embed(const int* __restrict__ x, const float* __restrict__ emb,
                        const float* __restrict__ pos, float* __restrict__ h) {
  int row = blockIdx.x;            // b*T + t
  int t = row & (TT - 1);
  int c = threadIdx.x * 4;
  int idx = x[row];
  float4 e = *(const float4*)(emb + (size_t)idx * DMODEL + c);
  float4 p = *(const float4*)(pos + (size_t)t * DMODEL + c);
  e.x += p.x; e.y += p.y; e.z += p.z; e.w += p.w;
  *(float4*)(h + (size_t)row * DMODEL + c) = e;
}

// ---------------- layernorm (one wave per 512-row) ----------------
template<int BF16OUT>
__global__ void k_ln(const float* __restrict__ in, const float* __restrict__ gam,
                     const float* __restrict__ bet, void* __restrict__ out) {
  int wid  = threadIdx.x >> 6;
  int lane = threadIdx.x & 63;
  int row  = blockIdx.x * 4 + wid;
  const float* p = in + (size_t)row * DMODEL + lane * 8;
  float4 v0 = *(const float4*)p;
  float4 v1 = *(const float4*)(p + 4);
  float vals[8] = {v0.x, v0.y, v0.z, v0.w, v1.x, v1.y, v1.z, v1.w};
  float s = 0.f;
  #pragma unroll
  for (int j = 0; j < 8; ++j) s += vals[j];
  #pragma unroll
  for (int m = 1; m < 64; m <<= 1) s += __shfl_xor(s, m);
  float mean = s * (1.f / DMODEL);
  float vsum = 0.f;
  #pragma unroll
  for (int j = 0; j < 8; ++j) { vals[j] -= mean; vsum += vals[j] * vals[j]; }
  #pragma unroll
  for (int m = 1; m < 64; m <<= 1) vsum += __shfl_xor(vsum, m);
  float inv = rsqrtf(vsum * (1.f / DMODEL) + 1e-5f);
  const float* gp = gam + lane * 8;
  const float* bp = bet + lane * 8;
  float4 g0 = *(const float4*)gp, g1 = *(const float4*)(gp + 4);
  float4 b0 = *(const float4*)bp, b1 = *(const float4*)(bp + 4);
  float gs[8] = {g0.x, g0.y, g0.z, g0.w, g1.x, g1.y, g1.z, g1.w};
  float bs[8] = {b0.x, b0.y, b0.z, b0.w, b1.x, b1.y, b1.z, b1.w};
  float ov[8];
  #pragma unroll
  for (int j = 0; j < 8; ++j) ov[j] = vals[j] * inv * gs[j] + bs[j];
  if (BF16OUT) {
    u16x8 o;
    #pragma unroll
    for (int j = 0; j < 8; ++j) o[j] = f2b(ov[j]);
    *(u16x8*)((unsigned short*)out + (size_t)row * DMODEL + lane * 8) = o;
  } else {
    float4 o0 = {ov[0], ov[1], ov[2], ov[3]};
    float4 o1 = {ov[4], ov[5], ov[6], ov[7]};
    float* q = (float*)out + (size_t)row * DMODEL + lane * 8;
    *(float4*)q = o0;
    *(float4*)(q + 4) = o1;
  }
}

// ---------------- bf16 MFMA GEMM (BN=128): C = A[M,K] * W[N,K]^T + bias ----------------
template<int RELU, int RESID, int OUTBF>
__device__ __forceinline__ void gemm_body(
    const unsigned short* __restrict__ A, const unsigned short* __restrict__ W,
    const float* __restrict__ bias, const float* resid,
    unsigned short* outb, float* outf, int M, int N, int K) {
  __shared__ __align__(16) unsigned short lsA[128 * 64];
  __shared__ __align__(16) unsigned short lsB[128 * 64];
  const int tid  = threadIdx.x;
  const int lane = tid & 63;
  const int wid  = tid >> 6;
  const int wr = wid >> 1, wc = wid & 1;
  const int l15 = lane & 15, g = lane >> 4;
  const int row0 = blockIdx.y * 128, col0 = blockIdx.x * 128;
  f32x4 acc[4][4] = {};
  for (int k0 = 0; k0 < K; k0 += 64) {
    #pragma unroll
    for (int p = 0; p < 4; ++p) {
      int s = p * 256 + tid;
      int r = s >> 3, seg = s & 7;
      gload16(A + (size_t)(row0 + r) * K + k0 + seg * 8, lsA + s * 8);
      gload16(W + (size_t)(col0 + r) * K + k0 + seg * 8, lsB + s * 8);
    }
    __syncthreads();
    #pragma unroll
    for (int ks = 0; ks < 2; ++ks) {
      bf16x8 af[4], bf[4];
      #pragma unroll
      for (int m = 0; m < 4; ++m)
        af[m] = *(const bf16x8*)&lsA[(wr * 64 + m * 16 + l15) * 64 + ks * 32 + g * 8];
      #pragma unroll
      for (int n = 0; n < 4; ++n)
        bf[n] = *(const bf16x8*)&lsB[(wc * 64 + n * 16 + l15) * 64 + ks * 32 + g * 8];
      #pragma unroll
      for (int m = 0; m < 4; ++m)
        #pragma unroll
        for (int n = 0; n < 4; ++n)
          acc[m][n] = mfma16(af[m], bf[n], acc[m][n]);
    }
    __syncthreads();
  }
  #pragma unroll
  for (int m = 0; m < 4; ++m) {
    const int grow = row0 + wr * 64 + m * 16 + g * 4;
    #pragma unroll
    for (int n = 0; n < 4; ++n) {
      const int gcol = col0 + wc * 64 + n * 16 + l15;
      const float bv = bias[gcol];
      #pragma unroll
      for (int r = 0; r < 4; ++r) {
        float v = acc[m][n][r] + bv;
        if (RESID) v += resid[(size_t)(grow + r) * N + gcol];
        if (RELU)  v = v > 0.f ? v : 0.f;
        if (OUTBF) outb[(size_t)(grow + r) * N + gcol] = f2b(v);
        else       outf[(size_t)(grow + r) * N + gcol] = v;
      }
    }
  }
}

template<int RELU, int RESID, int OUTBF>
__global__ __launch_bounds__(256)
void k_gemm(const unsigned short* __restrict__ A, const unsigned short* __restrict__ W,
            const float* __restrict__ bias, const float* resid,
            unsigned short* outb, float* outf, int M, int N, int K) {
  gemm_body<RELU, RESID, OUTBF>(A, W, bias, resid, outb, outf, M, N, K);
}

__global__ __launch_bounds__(256)
void k_gemm_qkv(const unsigned short* __restrict__ A,
                const unsigned short* Wq, const unsigned short* Wk, const unsigned short* Wv,
                const float* bq, const float* bk, const float* bv,
                unsigned short* q, unsigned short* k, unsigned short* v) {
  const unsigned short* W; const float* bias; unsigned short* out;
  if (blockIdx.z == 0)      { W = Wq; bias = bq; out = q; }
  else if (blockIdx.z == 1) { W = Wk; bias = bk; out = k; }
  else                      { W = Wv; bias = bv; out = v; }
  gemm_body<0, 0, 1>(A, W, bias, nullptr, out, nullptr, 4096, 512, 512);
}

// ---------------- bf16 MFMA GEMM (BN=64): for N=512 outputs (grid 8x32=256) -------------
template<int RELU, int RESID, int OUTBF>
__global__ __launch_bounds__(256)
void k_gemm64(const unsigned short* __restrict__ A, const unsigned short* __restrict__ W,
              const float* __restrict__ bias, const float* resid,
              unsigned short* outb, float* outf, int M, int N, int K) {
  __shared__ __align__(16) unsigned short lsA[128 * 64];
  __shared__ __align__(16) unsigned short lsB[64 * 64];
  const int tid  = threadIdx.x;
  const int lane = tid & 63;
  const int wid  = tid >> 6;
  const int wr = wid >> 1, wc = wid & 1;
  const int l15 = lane & 15, g = lane >> 4;
  const int row0 = blockIdx.y * 128, col0 = blockIdx.x * 64;
  f32x4 acc[4][2] = {};
  for (int k0 = 0; k0 < K; k0 += 64) {
    #pragma unroll
    for (int p = 0; p < 4; ++p) {
      int s = p * 256 + tid;
      int r = s >> 3, seg = s & 7;
      gload16(A + (size_t)(row0 + r) * K + k0 + seg * 8, lsA + s * 8);
    }
    #pragma unroll
    for (int p = 0; p < 2; ++p) {
      int s = p * 256 + tid;
      int r = s >> 3, seg = s & 7;
      gload16(W + (size_t)(col0 + r) * K + k0 + seg * 8, lsB + s * 8);
    }
    __syncthreads();
    #pragma unroll
    for (int ks = 0; ks < 2; ++ks) {
      bf16x8 af[4], bf[2];
      #pragma unroll
      for (int m = 0; m < 4; ++m)
        af[m] = *(const bf16x8*)&lsA[(wr * 64 + m * 16 + l15) * 64 + ks * 32 + g * 8];
      #pragma unroll
      for (int n = 0; n < 2; ++n)
        bf[n] = *(const bf16x8*)&lsB[(wc * 32 + n * 16 + l15) * 64 + ks * 32 + g * 8];
      #pragma unroll
      for (int m = 0; m < 4; ++m)
        #pragma unroll
        for (int n = 0; n < 2; ++n)
          acc[m][n] = mfma16(af[m], bf[n], acc[m][n]);
    }
    __syncthreads();
  }
  #pragma unroll
  for (int m = 0; m < 4; ++m) {
    const int grow = row0 + wr * 64 + m * 16 + g * 4;
    #pragma unroll
    for (int n = 0; n < 2; ++n) {
      const int gcol = col0 + wc * 32 + n * 16 + l15;
      const float bv = bias[gcol];
      #pragma unroll
      for (int r = 0; r < 4; ++r) {
        float v = acc[m][n][r] + bv;
        if (RESID) v += resid[(size_t)(grow + r) * N + gcol];
        if (RELU)  v = v > 0.f ? v : 0.f;
        if (OUTBF) outb[(size_t)(grow + r) * N + gcol] = f2b(v);
        else       outf[(size_t)(grow + r) * N + gcol] = v;
      }
    }
  }
}

// ---------------- V transpose: vt[bh][d][s] ----------------
__global__ __launch_bounds__(256)
void k_trans(const unsigned short* __restrict__ v, unsigned short* __restrict__ vt) {
  __shared__ unsigned short tile[64][72];
  const int bh = blockIdx.y;
  const int b = bh >> 3, hh = bh & 7;
  const int s0 = blockIdx.x * 64;
  const int tid = threadIdx.x;
  #pragma unroll
  for (int p = 0; p < 2; ++p) {
    int s = p * 256 + tid;
    int r = s >> 3, seg = s & 7;
    u16x8 vv = *(const u16x8*)(v + (size_t)(b * TT + s0 + r) * DMODEL + hh * HD + seg * 8);
    *(u16x8*)&tile[r][seg * 8] = vv;
  }
  __syncthreads();
  #pragma unroll
  for (int p = 0; p < 2; ++p) {
    int s = p * 256 + tid;
    int d = s >> 3, seg = s & 7;
    u16x8 ov;
    #pragma unroll
    for (int j = 0; j < 8; ++j) ov[j] = tile[seg * 8 + j][d];
    *(u16x8*)(vt + (size_t)(bh * HD + d) * TT + s0 + seg * 8) = ov;
  }
}

// ---------------- single-pass attention ----------------
// block = 1 head x 128 q-rows (8 waves x 16 rows). Barrier-free.
// Direct-global K/V with 1-step K register lookahead. Unnormalized exp -> pscr (u8 x24),
// row inv-sums -> sums; O accumulated unnormalized, scaled at end.
#define NSTEP1 64

#define ASTEP(c0, c1, c2, c3, n0, n1, n2, n3, s)                              \
  {                                                                           \
    const unsigned short* vp = vbase + (s) * 32 + g * 8;                      \
    u16x8 vv0 = *(const u16x8*)(vp + (size_t)(l15) * TT);                     \
    u16x8 vv1 = *(const u16x8*)(vp + (size_t)(16 + l15) * TT);                \
    u16x8 vv2 = *(const u16x8*)(vp + (size_t)(32 + l15) * TT);                \
    u16x8 vv3 = *(const u16x8*)(vp + (size_t)(48 + l15) * TT);                \
    if ((s) + 1 < NSTEP1) {                                                   \
      const unsigned short* kp = kbase + (size_t)((s) + 1) * 32 * DMODEL;     \
      n0 = *(const u16x8*)(kp + (size_t)l15 * DMODEL);                        \
      n1 = *(const u16x8*)(kp + (size_t)l15 * DMODEL + 32);                   \
      n2 = *(const u16x8*)(kp + (size_t)(16 + l15) * DMODEL);                 \
      n3 = *(const u16x8*)(kp + (size_t)(16 + l15) * DMODEL + 32);            \
    }                                                                         \
    f32x4 sf0 = {}, sf1 = {};                                                 \
    sf0 = mfma16(aq0, asbf(c0), sf0);                                         \
    sf0 = mfma16(aq1, asbf(c1), sf0);                                         \
    sf1 = mfma16(aq0, asbf(c2), sf1);                                         \
    sf1 = mfma16(aq1, asbf(c3), sf1);                                         \
    _Pragma("unroll")                                                         \
    for (int r = 0; r < 4; ++r) {                                             \
      float e0 = __expf(sf0[r] * 0.125f);                                     \
      float e1 = __expf(sf1[r] * 0.125f);                                     \
      ssum[r] += e0 + e1;                                                     \
      Ps[w][g * 4 + r][l15] = f2b(e0);                                        \
      Ps[w][g * 4 + r][16 + l15] = f2b(e1);                                   \
    }                                                                         \
    bf16x8 pa = *(const bf16x8*)&Ps[w][l15][g * 8];                           \
    u16x8 pst = *(const u16x8*)&Ps[w][lane >> 2][(lane & 3) * 8];             \
    *(uint2*)(pscr + pbase + (size_t)(lane >> 2) * TT + (s) * 32 +            \
              (lane & 3) * 8) = pack8(pst);                                   \
    o0 = mfma16(pa, asbf(vv0), o0);                                           \
    o1 = mfma16(pa, asbf(vv1), o1);                                           \
    o2 = mfma16(pa, asbf(vv2), o2);                                           \
    o3 = mfma16(pa, asbf(vv3), o3);                                           \
  }

__global__ __launch_bounds__(512)
void k_attn1(const unsigned short* __restrict__ q, const unsigned short* __restrict__ kk,
             const unsigned short* __restrict__ vt, unsigned short* __restrict__ ao,
             unsigned char* __restrict__ pscr, float* __restrict__ sums,
             int bh0, int plocal) {
  __shared__ __align__(16) unsigned short Ps[NH][16][40];   // 10 KB
  const int tid  = threadIdx.x;
  const int lane = tid & 63;
  const int w    = tid >> 6;
  const int l15  = lane & 15;
  const int g    = lane >> 4;
  const int qt   = blockIdx.x;        // tiles of 128 q-rows
  const int bh   = bh0 + blockIdx.y;
  const int b    = bh >> 3, h = bh & 7;
  const int row0 = qt * 128 + w * 16; // this wave's 16 q-rows
  const int pi   = plocal ? (int)blockIdx.y : bh;

  const unsigned short* kbase = kk + (size_t)(b * TT) * DMODEL + h * HD + g * 8;
  const unsigned short* vbase = vt + (size_t)bh * HD * TT;
  const size_t pbase = ((size_t)pi * TT + row0) * TT;

  const size_t qoff = (size_t)(b * TT + row0 + l15) * DMODEL + h * HD + g * 8;
  const bf16x8 aq0 = *(const bf16x8*)(q + qoff);
  const bf16x8 aq1 = *(const bf16x8*)(q + qoff + 32);

  f32x4 o0 = {}, o1 = {}, o2 = {}, o3 = {};
  float ssum[4] = {0.f, 0.f, 0.f, 0.f};

  u16x8 kA0, kA1, kA2, kA3, kB0, kB1, kB2, kB3;
  {
    const unsigned short* kp = kbase;
    kA0 = *(const u16x8*)(kp + (size_t)l15 * DMODEL);
    kA1 = *(const u16x8*)(kp + (size_t)l15 * DMODEL + 32);
    kA2 = *(const u16x8*)(kp + (size_t)(16 + l15) * DMODEL);
    kA3 = *(const u16x8*)(kp + (size_t)(16 + l15) * DMODEL + 32);
  }
  for (int s = 0; s < NSTEP1; s += 2) {
    ASTEP(kA0, kA1, kA2, kA3, kB0, kB1, kB2, kB3, s);
    ASTEP(kB0, kB1, kB2, kB3, kA0, kA1, kA2, kA3, s + 1);
  }

  #pragma unroll
  for (int r = 0; r < 4; ++r) {
    float sv = ssum[r];
    sv += __shfl_xor(sv, 1);
    sv += __shfl_xor(sv, 2);
    sv += __shfl_xor(sv, 4);
    sv += __shfl_xor(sv, 8);
    float inv = 1.f / sv;
    if (l15 == 0) sums[(size_t)bh * TT + row0 + g * 4 + r] = inv;
    o0[r] *= inv; o1[r] *= inv; o2[r] *= inv; o3[r] *= inv;
  }
  #pragma unroll
  for (int r = 0; r < 4; ++r) {
    size_t arow = (size_t)(b * TT + row0 + g * 4 + r) * DMODEL + h * HD;
    ao[arow + l15]      = f2b(o0[r]);
    ao[arow + 16 + l15] = f2b(o1[r]);
    ao[arow + 32 + l15] = f2b(o2[r]);
    ao[arow + 48 + l15] = f2b(o3[r]);
  }
}

// ---------------- head-average from u8 scratch ----------------
__global__ __launch_bounds__(256)
void k_avg(const unsigned char* __restrict__ pscr, const float* __restrict__ sums,
           float* __restrict__ avg, int b0, int plocal) {
  const int i = blockIdx.x, b = b0 + blockIdx.y;
  const int j0 = threadIdx.x * 8;
  float acc[8] = {};
  #pragma unroll
  for (int hh = 0; hh < 8; ++hh) {
    float inv = sums[(size_t)(b * 8 + hh) * TT + i];
    int pi = plocal ? hh : (b * 8 + hh);
    uint2 p = *(const uint2*)(pscr + ((size_t)pi * TT + i) * TT + j0);
    #pragma unroll
    for (int jj = 0; jj < 4; ++jj) {
      acc[jj]     += (float)((p.x >> (8 * jj)) & 255u) * inv;
      acc[4 + jj] += (float)((p.y >> (8 * jj)) & 255u) * inv;
    }
  }
  const float sc = 1.f / (24.f * 8.f);
  float4 q0 = {acc[0] * sc, acc[1] * sc, acc[2] * sc, acc[3] * sc};
  float4 q1 = {acc[4] * sc, acc[5] * sc, acc[6] * sc, acc[7] * sc};
  float* op = avg + ((size_t)(b * TT + i)) * TT + j0;
  *(float4*)op = q0;
  *(float4*)(op + 4) = q1;
}

// ---------------- two-pass attention with in-LDS avg (fallback only) ----------------
#define KS 32
#define NSTEP (TT / KS)

__device__ __forceinline__ void loadK(const unsigned short* src, u16x8* kr) {
  int row = threadIdx.x >> 4, c0 = (threadIdx.x & 15) * 8;
  const unsigned short* p = src + row * 512 + c0;
  #pragma unroll
  for (int j = 0; j < 4; ++j) kr[j] = *(const u16x8*)(p + j * 128);
}
__device__ __forceinline__ void writeK(unsigned short* Kt, const u16x8* kr) {
  int row = threadIdx.x >> 4, c0 = (threadIdx.x & 15) * 8, sw = (row & 7) << 3;
  #pragma unroll
  for (int j = 0; j < 4; ++j)
    *(u16x8*)(Kt + row * 512 + ((c0 + j * 128) ^ sw)) = kr[j];
}
__device__ __forceinline__ void loadV(const unsigned short* vt_b, int s0, u16x8* vr) {
  const unsigned short* p = vt_b + (size_t)threadIdx.x * TT + s0;
  #pragma unroll
  for (int j = 0; j < 4; ++j) vr[j] = *(const u16x8*)(p + j * 8);
}
__device__ __forceinline__ void writeV(unsigned short* Vt, const u16x8* vr) {
  int row = threadIdx.x, sw = ((row >> 1) & 3) << 3;
  #pragma unroll
  for (int j = 0; j < 4; ++j)
    *(u16x8*)(Vt + row * 32 + ((j * 8) ^ sw)) = vr[j];
}

__global__ __launch_bounds__(512)
void k_attn(const unsigned short* __restrict__ q, const unsigned short* __restrict__ kk,
            const unsigned short* __restrict__ vt, unsigned short* __restrict__ ao,
            float* __restrict__ avg) {
  __shared__ __align__(16) unsigned short Kt[2][KS * 512];
  __shared__ __align__(16) unsigned short Vt[2][512 * KS];
  __shared__ __align__(16) unsigned short Pb[2][NH][16][40];
  const int tid  = threadIdx.x;
  const int lane = tid & 63;
  const int w    = tid >> 6;
  const int l15  = lane & 15;
  const int g    = lane >> 4;
  const int qt   = blockIdx.x;
  const int b    = blockIdx.y;

  const unsigned short* kbase = kk + (size_t)(b * TT) * DMODEL;
  const unsigned short* vbase = vt + (size_t)b * DMODEL * TT;

  const size_t qoff = (size_t)(b * TT + qt * 16 + l15) * DMODEL + w * HD + g * 8;
  const bf16x8 aq0 = *(const bf16x8*)(q + qoff);
  const bf16x8 aq1 = *(const bf16x8*)(q + qoff + 32);

  u16x8 kr[4], vr[4];

  float ssum[4] = {0.f, 0.f, 0.f, 0.f};
  loadK(kbase, kr);
  writeK(Kt[0], kr);
  __syncthreads();
  for (int s = 0; s < NSTEP; ++s) {
    const int cur = s & 1;
    if (s < NSTEP - 1) loadK(kbase + (size_t)(s + 1) * KS * 512, kr);
    f32x4 sf[2] = {};
    #pragma unroll
    for (int n = 0; n < 2; ++n) {
      const int row = n * 16 + l15, sw = (row & 7) << 3;
      const unsigned short* kp = Kt[cur] + row * 512;
      bf16x8 b0 = *(const bf16x8*)(kp + ((w * 64 + g * 8) ^ sw));
      bf16x8 b1 = *(const bf16x8*)(kp + ((w * 64 + 32 + g * 8) ^ sw));
      sf[n] = mfma16(aq0, b0, sf[n]);
      sf[n] = mfma16(aq1, b1, sf[n]);
    }
    #pragma unroll
    for (int r = 0; r < 4; ++r)
      ssum[r] += __expf(sf[0][r] * 0.125f) + __expf(sf[1][r] * 0.125f);
    if (s < NSTEP - 1) writeK(Kt[cur ^ 1], kr);
    __syncthreads();
  }
  float inv_s[4];
  #pragma unroll
  for (int r = 0; r < 4; ++r) {
    float v = ssum[r];
    v += __shfl_xor(v, 1);
    v += __shfl_xor(v, 2);
    v += __shfl_xor(v, 4);
    v += __shfl_xor(v, 8);
    inv_s[r] = 1.f / v;
  }

  f32x4 o[4] = {};
  loadK(kbase, kr);
  loadV(vbase, 0, vr);
  writeK(Kt[0], kr);
  writeV(Vt[0], vr);
  __syncthreads();
  for (int s = 0; s < NSTEP; ++s) {
    const int cur = s & 1;
    if (s < NSTEP - 1) {
      loadK(kbase + (size_t)(s + 1) * KS * 512, kr);
      loadV(vbase, (s + 1) * KS, vr);
    }
    f32x4 sf[2] = {};
    #pragma unroll
    for (int n = 0; n < 2; ++n) {
      const int row = n * 16 + l15, sw = (row & 7) << 3;
      const unsigned short* kp = Kt[cur] + row * 512;
      bf16x8 b0 = *(const bf16x8*)(kp + ((w * 64 + g * 8) ^ sw));
      bf16x8 b1 = *(const bf16x8*)(kp + ((w * 64 + 32 + g * 8) ^ sw));
      sf[n] = mfma16(aq0, b0, sf[n]);
      sf[n] = mfma16(aq1, b1, sf[n]);
    }
    #pragma unroll
    for (int n = 0; n < 2; ++n)
      #pragma unroll
      for (int r = 0; r < 4; ++r)
        Pb[cur][w][g * 4 + r][n * 16 + l15] = f2b(__expf(sf[n][r] * 0.125f) * inv_s[r]);
    __syncthreads();

    bf16x8 pa = *(const bf16x8*)&Pb[cur][w][l15][g * 8];
    #pragma unroll
    for (int n = 0; n < 4; ++n) {
      const int row = w * 64 + n * 16 + l15;
      bf16x8 bv = *(const bf16x8*)(Vt[cur] + row * 32 + ((g * 8) ^ (((row >> 1) & 3) << 3)));
      o[n] = mfma16(pa, bv, o[n]);
    }
    {
      int i = tid >> 5, j = tid & 31;
      float sm = 0.f;
      #pragma unroll
      for (int hh = 0; hh < NH; ++hh) sm += b2f(Pb[cur][hh][i][j]);
      avg[(size_t)(b * TT + qt * 16 + i) * TT + s * KS + j] = sm * 0.125f;
    }
    if (s < NSTEP - 1) {
      writeK(Kt[cur ^ 1], kr);
      writeV(Vt[cur ^ 1], vr);
    }
    __syncthreads();
  }

  #pragma unroll
  for (int n = 0; n < 4; ++n)
    #pragma unroll
    for (int r = 0; r < 4; ++r)
      ao[(size_t)(b * TT + qt * 16 + g * 4 + r) * DMODEL + w * HD + n * 16 + l15] = f2b(o[n][r]);
}

// ---------------- final mean over T ----------------
__global__ void k_mean(const float* __restrict__ hf, float* __restrict__ out) {
  int c = blockIdx.x * 256 + threadIdx.x;
  int b = blockIdx.y;
  int t0 = blockIdx.z * 128;
  float s = 0.f;
  for (int t = 0; t < 128; ++t)
    s += hf[(size_t)(b * TT + t0 + t) * DMODEL + c];
  atomicAdd(&out[b * DMODEL + c], s * (1.f / TT));
}

extern "C" void kernel_launch(void* const* d_in, const int* in_sizes, int n_in,
                              void* d_out, int out_size, void* d_ws, size_t ws_size,
                              hipStream_t stream) {
  const int*   x    = (const int*)d_in[0];
  const float* emb  = (const float*)d_in[1];
  const float* pos  = (const float*)d_in[2];
  const float* Wq   = (const float*)d_in[3];
  const float* bq   = (const float*)d_in[4];
  const float* Wk   = (const float*)d_in[5];
  const float* bk   = (const float*)d_in[6];
  const float* Wv   = (const float*)d_in[7];
  const float* bv   = (const float*)d_in[8];
  const float* Wo   = (const float*)d_in[9];
  const float* bo   = (const float*)d_in[10];
  const float* W1   = (const float*)d_in[11];
  const float* b1   = (const float*)d_in[12];
  const float* W2   = (const float*)d_in[13];
  const float* b2   = (const float*)d_in[14];
  const float* ln1g = (const float*)d_in[15];
  const float* ln1b = (const float*)d_in[16];
  const float* ln2g = (const float*)d_in[17];
  const float* ln2b = (const float*)d_in[18];
  const float* lnfg = (const float*)d_in[19];
  const float* lnfb = (const float*)d_in[20];

  char* w = (char*)d_ws;
  const size_t MB = 1024 * 1024;
  unsigned short* wqb = (unsigned short*)(w + 0 * MB);
  unsigned short* wkb = (unsigned short*)(w + 2 * MB);
  unsigned short* wvb = (unsigned short*)(w + 4 * MB);
  unsigned short* wob = (unsigned short*)(w + 6 * MB);
  unsigned short* w1b = (unsigned short*)(w + 8 * MB);
  unsigned short* w2b = (unsigned short*)(w + 16 * MB);
  float*          h   = (float*)(w + 24 * MB);
  unsigned short* hn  = (unsigned short*)(w + 32 * MB);
  unsigned short* qb  = (unsigned short*)(w + 36 * MB);
  unsigned short* kb  = (unsigned short*)(w + 40 * MB);
  unsigned short* vb  = (unsigned short*)(w + 44 * MB);
  unsigned short* vtb = (unsigned short*)(w + 48 * MB);
  unsigned short* ab  = (unsigned short*)(w + 52 * MB);
  unsigned short* ff  = (unsigned short*)(w + 56 * MB);   // 16 MB
  float*          sums = (float*)(w + 72 * MB);           // 128 KB
  unsigned char*  pscr_ws = (unsigned char*)(w + 73 * MB);
  float*          hf  = (float*)(w + 36 * MB);            // reuse q space after layers

  k_f2b<<<1024, 256, 0, stream>>>(Wq, wqb, 262144);
  k_f2b<<<1024, 256, 0, stream>>>(Wk, wkb, 262144);
  k_f2b<<<1024, 256, 0, stream>>>(Wv, wvb, 262144);
  k_f2b<<<1024, 256, 0, stream>>>(Wo, wob, 262144);
  k_f2b<<<4096, 256, 0, stream>>>(W1, w1b, 1048576);
  k_f2b<<<4096, 256, 0, stream>>>(W2, w2b, 1048576);

  k_embed<<<BB * TT, 128, 0, stream>>>(x, emb, pos, h);

  float* attn_maps = (float*)d_out + 1024;
  const size_t RSZ = (size_t)BB * TT * TT;               // floats per map region (32 MiB)
  const size_t NEED_FULL = 73 * MB + 64 * MB;            // ws pscr, both batches
  const size_t NEED_HALF = 73 * MB + 32 * MB;            // ws pscr, one batch

  for (int l = 0; l < 4; ++l) {
    k_ln<1><<<BB * TT / 4, 256, 0, stream>>>(h, ln1g + l * DMODEL, ln1b + l * DMODEL, hn);
    dim3 gq(DMODEL / 128, BB * TT / 128, 3);
    k_gemm_qkv<<<gq, 256, 0, stream>>>(hn,
        wqb + (size_t)l * DMODEL * DMODEL, wkb + (size_t)l * DMODEL * DMODEL,
        wvb + (size_t)l * DMODEL * DMODEL,
        bq + l * DMODEL, bk + l * DMODEL, bv + l * DMODEL, qb, kb, vb);
    k_trans<<<dim3(TT / 64, BB * NH), 256, 0, stream>>>(vb, vtb);

    float* maps_l = attn_maps + (size_t)l * RSZ;
    if (l <= 1) {
      // u8 pscr = exactly 2 future map regions (l+1, l+2)
      unsigned char* ps = (unsigned char*)(attn_maps + (size_t)(l + 1) * RSZ);
      k_attn1<<<dim3(TT / 128, BB * NH), 512, 0, stream>>>(qb, kb, vtb, ab, ps, sums, 0, 0);
      k_avg<<<dim3(TT, BB), 256, 0, stream>>>(ps, sums, maps_l, 0, 0);
    } else if (l == 2) {
      // only region 3 free: split by batch (32 MiB each round)
      unsigned char* ps = (unsigned char*)(attn_maps + (size_t)3 * RSZ);
      for (int b = 0; b < BB; ++b) {
        k_attn1<<<dim3(TT / 128, NH), 512, 0, stream>>>(qb, kb, vtb, ab, ps, sums, b * NH, 1);
        k_avg<<<dim3(TT, 1), 256, 0, stream>>>(ps, sums, maps_l, b, 1);
      }
    } else {
      if (ws_size >= NEED_FULL) {
        k_attn1<<<dim3(TT / 128, BB * NH), 512, 0, stream>>>(qb, kb, vtb, ab, pscr_ws, sums, 0, 0);
        k_avg<<<dim3(TT, BB), 256, 0, stream>>>(pscr_ws, sums, maps_l, 0, 0);
      } else if (ws_size >= NEED_HALF) {
        for (int b = 0; b < BB; ++b) {
          k_attn1<<<dim3(TT / 128, NH), 512, 0, stream>>>(qb, kb, vtb, ab, pscr_ws, sums, b * NH, 1);
          k_avg<<<dim3(TT, 1), 256, 0, stream>>>(pscr_ws, sums, maps_l, b, 1);
        }
      } else {
        k_attn<<<dim3(TT / 16, BB), 512, 0, stream>>>(qb, kb, vtb, ab, maps_l);
      }
    }

    k_gemm64<0, 1, 0><<<dim3(DMODEL / 64, BB * TT / 128), 256, 0, stream>>>(ab,
        wob + (size_t)l * DMODEL * DMODEL, bo + l * DMODEL, h, nullptr, h, 4096, 512, 512);
    k_ln<1><<<BB * TT / 4, 256, 0, stream>>>(h, ln2g + l * DMODEL, ln2b + l * DMODEL, hn);
    k_gemm<1, 0, 1><<<dim3(DFF / 128, BB * TT / 128), 256, 0, stream>>>(hn,
        w1b + (size_t)l * DFF * DMODEL, b1 + l * DFF, nullptr, ff, nullptr, 4096, 2048, 512);
    k_gemm64<0, 1, 0><<<dim3(DMODEL / 64, BB * TT / 128), 256, 0, stream>>>(ff,
        w2b + (size_t)l * DMODEL * DFF, b2 + l * DMODEL, h, nullptr, h, 4096, 512, 2048);
  }
  k_ln<0><<<BB * TT / 4, 256, 0, stream>>>(h, lnfg, lnfb, hf);
  hipMemsetAsync(d_out, 0, 1024 * sizeof(float), stream);
  k_mean<<<dim3(2, BB, 16), 256, 0, stream>>>(hf, (float*)d_out);
}

// Round 6
// 1079.955 us; speedup vs baseline: 1.2753x; 1.2753x over previous
//
#include <hip/hip_runtime.h>
#include <stdint.h>

using bf16x8 = __attribute__((ext_vector_type(8))) __bf16;
using u16x8  = __attribute__((ext_vector_type(8))) unsigned short;
using f32x4  = __attribute__((ext_vector_type(4))) float;

#define DMODEL 512
#define DFF    2048
#define TT     2048
#define BB     2
#define NH     8
#define HD     64

__device__ __forceinline__ unsigned short f2b(float f) {
  union { float f; uint32_t u; } c; c.f = f;
  uint32_t u = c.u;
  uint32_t r = (u + 0x7FFFu + ((u >> 16) & 1u)) >> 16;
  return (unsigned short)r;
}
__device__ __forceinline__ float b2f(unsigned short s) {
  union { uint32_t u; float f; } c; c.u = ((uint32_t)s) << 16;
  return c.f;
}
__device__ __forceinline__ bf16x8 asbf(u16x8 x) { return __builtin_bit_cast(bf16x8, x); }

__device__ __forceinline__ f32x4 mfma16(bf16x8 a, bf16x8 b, f32x4 c) {
  return __builtin_amdgcn_mfma_f32_16x16x32_bf16(a, b, c, 0, 0, 0);
}

__device__ __forceinline__ void gload16(const void* g, void* l) {
  __builtin_amdgcn_global_load_lds((__attribute__((address_space(1))) void*)(g),
                                   (__attribute__((address_space(3))) void*)(l),
                                   16, 0, 0);
}

// ---------------- f32 -> bf16 convert (weights) ----------------
__global__ void k_f2b(const float* __restrict__ in, unsigned short* __restrict__ out, int n4) {
  int i = blockIdx.x * blockDim.x + threadIdx.x;
  if (i < n4) {
    float4 v = ((const float4*)in)[i];
    ushort4 o;
    o.x = f2b(v.x); o.y = f2b(v.y); o.z = f2b(v.z); o.w = f2b(v.w);
    ((ushort4*)out)[i] = o;
  }
}

// ---------------- embedding + positional ----------------
__global__ void k_embed(const int* __restrict__ x, const float* __restrict__ emb,
                        const float* __restrict__ pos, float* __restrict__ h) {
  int row = blockIdx.x;            // b*T + t
  int t = row & (TT - 1);
  int c = threadIdx.x * 4;
  int idx = x[row];
  float4 e = *(const float4*)(emb + (size_t)idx * DMODEL + c);
  float4 p = *(const float4*)(pos + (size_t)t * DMODEL + c);
  e.x += p.x; e.y += p.y; e.z += p.z; e.w += p.w;
  *(float4*)(h + (size_t)row * DMODEL + c) = e;
}

// ---------------- layernorm (one wave per 512-row) ----------------
template<int BF16OUT>
__global__ void k_ln(const float* __restrict__ in, const float* __restrict__ gam,
                     const float* __restrict__ bet, void* __restrict__ out) {
  int wid  = threadIdx.x >> 6;
  int lane = threadIdx.x & 63;
  int row  = blockIdx.x * 4 + wid;
  const float* p = in + (size_t)row * DMODEL + lane * 8;
  float4 v0 = *(const float4*)p;
  float4 v1 = *(const float4*)(p + 4);
  float vals[8] = {v0.x, v0.y, v0.z, v0.w, v1.x, v1.y, v1.z, v1.w};
  float s = 0.f;
  #pragma unroll
  for (int j = 0; j < 8; ++j) s += vals[j];
  #pragma unroll
  for (int m = 1; m < 64; m <<= 1) s += __shfl_xor(s, m);
  float mean = s * (1.f / DMODEL);
  float vsum = 0.f;
  #pragma unroll
  for (int j = 0; j < 8; ++j) { vals[j] -= mean; vsum += vals[j] * vals[j]; }
  #pragma unroll
  for (int m = 1; m < 64; m <<= 1) vsum += __shfl_xor(vsum, m);
  float inv = rsqrtf(vsum * (1.f / DMODEL) + 1e-5f);
  const float* gp = gam + lane * 8;
  const float* bp = bet + lane * 8;
  float4 g0 = *(const float4*)gp, g1 = *(const float4*)(gp + 4);
  float4 b0 = *(const float4*)bp, b1 = *(const float4*)(bp + 4);
  float gs[8] = {g0.x, g0.y, g0.z, g0.w, g1.x, g1.y, g1.z, g1.w};
  float bs[8] = {b0.x, b0.y, b0.z, b0.w, b1.x, b1.y, b1.z, b1.w};
  float ov[8];
  #pragma unroll
  for (int j = 0; j < 8; ++j) ov[j] = vals[j] * inv * gs[j] + bs[j];
  if (BF16OUT) {
    u16x8 o;
    #pragma unroll
    for (int j = 0; j < 8; ++j) o[j] = f2b(ov[j]);
    *(u16x8*)((unsigned short*)out + (size_t)row * DMODEL + lane * 8) = o;
  } else {
    float4 o0 = {ov[0], ov[1], ov[2], ov[3]};
    float4 o1 = {ov[4], ov[5], ov[6], ov[7]};
    float* q = (float*)out + (size_t)row * DMODEL + lane * 8;
    *(float4*)q = o0;
    *(float4*)(q + 4) = o1;
  }
}

// ---------------- bf16 MFMA GEMM (BN=128): C = A[M,K] * W[N,K]^T + bias ----------------
template<int RELU, int RESID, int OUTBF>
__device__ __forceinline__ void gemm_body(
    const unsigned short* __restrict__ A, const unsigned short* __restrict__ W,
    const float* __restrict__ bias, const float* resid,
    unsigned short* outb, float* outf, int M, int N, int K) {
  __shared__ __align__(16) unsigned short lsA[128 * 64];
  __shared__ __align__(16) unsigned short lsB[128 * 64];
  const int tid  = threadIdx.x;
  const int lane = tid & 63;
  const int wid  = tid >> 6;
  const int wr = wid >> 1, wc = wid & 1;
  const int l15 = lane & 15, g = lane >> 4;
  const int row0 = blockIdx.y * 128, col0 = blockIdx.x * 128;
  f32x4 acc[4][4] = {};
  for (int k0 = 0; k0 < K; k0 += 64) {
    #pragma unroll
    for (int p = 0; p < 4; ++p) {
      int s = p * 256 + tid;
      int r = s >> 3, seg = s & 7;
      gload16(A + (size_t)(row0 + r) * K + k0 + seg * 8, lsA + s * 8);
      gload16(W + (size_t)(col0 + r) * K + k0 + seg * 8, lsB + s * 8);
    }
    __syncthreads();
    #pragma unroll
    for (int ks = 0; ks < 2; ++ks) {
      bf16x8 af[4], bf[4];
      #pragma unroll
      for (int m = 0; m < 4; ++m)
        af[m] = *(const bf16x8*)&lsA[(wr * 64 + m * 16 + l15) * 64 + ks * 32 + g * 8];
      #pragma unroll
      for (int n = 0; n < 4; ++n)
        bf[n] = *(const bf16x8*)&lsB[(wc * 64 + n * 16 + l15) * 64 + ks * 32 + g * 8];
      #pragma unroll
      for (int m = 0; m < 4; ++m)
        #pragma unroll
        for (int n = 0; n < 4; ++n)
          acc[m][n] = mfma16(af[m], bf[n], acc[m][n]);
    }
    __syncthreads();
  }
  #pragma unroll
  for (int m = 0; m < 4; ++m) {
    const int grow = row0 + wr * 64 + m * 16 + g * 4;
    #pragma unroll
    for (int n = 0; n < 4; ++n) {
      const int gcol = col0 + wc * 64 + n * 16 + l15;
      const float bv = bias[gcol];
      #pragma unroll
      for (int r = 0; r < 4; ++r) {
        float v = acc[m][n][r] + bv;
        if (RESID) v += resid[(size_t)(grow + r) * N + gcol];
        if (RELU)  v = v > 0.f ? v : 0.f;
        if (OUTBF) outb[(size_t)(grow + r) * N + gcol] = f2b(v);
        else       outf[(size_t)(grow + r) * N + gcol] = v;
      }
    }
  }
}

template<int RELU, int RESID, int OUTBF>
__global__ __launch_bounds__(256)
void k_gemm(const unsigned short* __restrict__ A, const unsigned short* __restrict__ W,
            const float* __restrict__ bias, const float* resid,
            unsigned short* outb, float* outf, int M, int N, int K) {
  gemm_body<RELU, RESID, OUTBF>(A, W, bias, resid, outb, outf, M, N, K);
}

__global__ __launch_bounds__(256)
void k_gemm_qkv(const unsigned short* __restrict__ A,
                const unsigned short* Wq, const unsigned short* Wk, const unsigned short* Wv,
                const float* bq, const float* bk, const float* bv,
                unsigned short* q, unsigned short* k, unsigned short* v) {
  const unsigned short* W; const float* bias; unsigned short* out;
  if (blockIdx.z == 0)      { W = Wq; bias = bq; out = q; }
  else if (blockIdx.z == 1) { W = Wk; bias = bk; out = k; }
  else                      { W = Wv; bias = bv; out = v; }
  gemm_body<0, 0, 1>(A, W, bias, nullptr, out, nullptr, 4096, 512, 512);
}

// ---------------- V transpose: vt[bh][d][s] ----------------
__global__ __launch_bounds__(256)
void k_trans(const unsigned short* __restrict__ v, unsigned short* __restrict__ vt) {
  __shared__ unsigned short tile[64][72];
  const int bh = blockIdx.y;
  const int b = bh >> 3, hh = bh & 7;
  const int s0 = blockIdx.x * 64;
  const int tid = threadIdx.x;
  #pragma unroll
  for (int p = 0; p < 2; ++p) {
    int s = p * 256 + tid;
    int r = s >> 3, seg = s & 7;
    u16x8 vv = *(const u16x8*)(v + (size_t)(b * TT + s0 + r) * DMODEL + hh * HD + seg * 8);
    *(u16x8*)&tile[r][seg * 8] = vv;
  }
  __syncthreads();
  #pragma unroll
  for (int p = 0; p < 2; ++p) {
    int s = p * 256 + tid;
    int d = s >> 3, seg = s & 7;
    u16x8 ov;
    #pragma unroll
    for (int j = 0; j < 8; ++j) ov[j] = tile[seg * 8 + j][d];
    *(u16x8*)(vt + (size_t)(bh * HD + d) * TT + s0 + seg * 8) = ov;
  }
}

// ---------------- single-pass attention, LDS-staged (all layers) ----------------
// block = 4 waves x 64 q-rows x 1 head; grid (T/64, nbh) = 512 blocks -> 2 blocks/CU.
// Per 64-key step: K[64x64] + V^T[64x64] staged once per block (XOR-swizzled,
// conflict-free ds_read_b128 frags), 1 barrier/step, 2-step global lookahead in regs.
// Unnormalized exp -> pscr (u8 x24); row inv-sums -> sums; O normalized at end.
#define KB2 64
#define NST2 (TT / KB2)

__global__ __launch_bounds__(256)
void k_attn1(const unsigned short* __restrict__ q, const unsigned short* __restrict__ kk,
             const unsigned short* __restrict__ vt, unsigned short* __restrict__ ao,
             unsigned char* __restrict__ pscr, float* __restrict__ sums,
             int bh0, int plocal) {
  __shared__ __align__(16) unsigned short Kt[2][KB2 * 64];   // [key][dim] 8KB each
  __shared__ __align__(16) unsigned short Vt[2][KB2 * 64];   // [dim][key] 8KB each
  __shared__ __align__(16) unsigned short Ps[4][16][72];     // per-wave P, 9KB
  const int tid  = threadIdx.x;
  const int lane = tid & 63;
  const int w    = tid >> 6;
  const int l15  = lane & 15;
  const int g    = lane >> 4;
  const int qt   = blockIdx.x;                 // 64-row q tile
  const int bh   = bh0 + blockIdx.y;
  const int b    = bh >> 3, h = bh & 7;
  const int pi   = plocal ? (int)blockIdx.y : bh;
  const int row0 = qt * 64 + w * 16;           // wave's q rows

  const int sr  = tid >> 2;                    // staging row 0..63
  const int sc  = tid & 3;                     // 32B chunk
  const int swz = (sr & 7) << 3;               // u16 XOR (16B granular)
  const unsigned short* kgp = kk + (size_t)(b * TT) * DMODEL + h * HD;
  const unsigned short* vgp = vt + (size_t)(bh * HD) * TT;

  const size_t qoff = (size_t)(b * TT + row0 + l15) * DMODEL + h * HD + g * 8;
  const bf16x8 aq0 = *(const bf16x8*)(q + qoff);
  const bf16x8 aq1 = *(const bf16x8*)(q + qoff + 32);

  f32x4 o[4] = {};
  float ssum[4] = {0.f, 0.f, 0.f, 0.f};

  u16x8 ks0, ks1, vs0, vs1;
  {
    const unsigned short* kp = kgp + (size_t)sr * DMODEL + sc * 16;
    ks0 = *(const u16x8*)kp;
    ks1 = *(const u16x8*)(kp + 8);
    const unsigned short* vp = vgp + (size_t)sr * TT + sc * 16;
    vs0 = *(const u16x8*)vp;
    vs1 = *(const u16x8*)(vp + 8);
  }
  *(u16x8*)&Kt[0][sr * 64 + ((sc * 16) ^ swz)]     = ks0;
  *(u16x8*)&Kt[0][sr * 64 + ((sc * 16 + 8) ^ swz)] = ks1;
  *(u16x8*)&Vt[0][sr * 64 + ((sc * 16) ^ swz)]     = vs0;
  *(u16x8*)&Vt[0][sr * 64 + ((sc * 16 + 8) ^ swz)] = vs1;
  {
    const unsigned short* kp = kgp + (size_t)(KB2 + sr) * DMODEL + sc * 16;
    ks0 = *(const u16x8*)kp;
    ks1 = *(const u16x8*)(kp + 8);
    const unsigned short* vp = vgp + (size_t)sr * TT + KB2 + sc * 16;
    vs0 = *(const u16x8*)vp;
    vs1 = *(const u16x8*)(vp + 8);
  }
  __syncthreads();

  for (int s = 0; s < NST2; ++s) {
    const int cur = s & 1;
    if (s + 1 < NST2) {
      *(u16x8*)&Kt[cur ^ 1][sr * 64 + ((sc * 16) ^ swz)]     = ks0;
      *(u16x8*)&Kt[cur ^ 1][sr * 64 + ((sc * 16 + 8) ^ swz)] = ks1;
      *(u16x8*)&Vt[cur ^ 1][sr * 64 + ((sc * 16) ^ swz)]     = vs0;
      *(u16x8*)&Vt[cur ^ 1][sr * 64 + ((sc * 16 + 8) ^ swz)] = vs1;
    }
    if (s + 2 < NST2) {
      const unsigned short* kp = kgp + (size_t)((s + 2) * KB2 + sr) * DMODEL + sc * 16;
      ks0 = *(const u16x8*)kp;
      ks1 = *(const u16x8*)(kp + 8);
      const unsigned short* vp = vgp + (size_t)sr * TT + (s + 2) * KB2 + sc * 16;
      vs0 = *(const u16x8*)vp;
      vs1 = *(const u16x8*)(vp + 8);
    }

    // S = Q K^T for 16 q-rows x 64 keys
    f32x4 sf[4];
    #pragma unroll
    for (int n = 0; n < 4; ++n) {
      const int kr = n * 16 + l15;
      const int ksw = (kr & 7) << 3;
      const unsigned short* kp = &Kt[cur][kr * 64];
      f32x4 c = {};
      c = mfma16(aq0, *(const bf16x8*)(kp + ((g * 8) ^ ksw)), c);
      c = mfma16(aq1, *(const bf16x8*)(kp + ((32 + g * 8) ^ ksw)), c);
      sf[n] = c;
    }
    // exp -> ssum + wave-local P tile
    #pragma unroll
    for (int n = 0; n < 4; ++n)
      #pragma unroll
      for (int r = 0; r < 4; ++r) {
        float e = __expf(sf[n][r] * 0.125f);
        ssum[r] += e;
        Ps[w][g * 4 + r][n * 16 + l15] = f2b(e);
      }
    // PV
    #pragma unroll
    for (int kc = 0; kc < 2; ++kc) {
      bf16x8 pa = *(const bf16x8*)&Ps[w][l15][kc * 32 + g * 8];
      #pragma unroll
      for (int n = 0; n < 4; ++n) {
        const int dr = n * 16 + l15;
        const int vsw = (dr & 7) << 3;
        bf16x8 bv = *(const bf16x8*)(&Vt[cur][dr * 64] + ((kc * 32 + g * 8) ^ vsw));
        o[n] = mfma16(pa, bv, o[n]);
      }
    }
    // pscr u8 store: lane covers row (lane>>2), 16 keys
    {
      const unsigned short* pr = &Ps[w][lane >> 2][(lane & 3) * 16];
      u16x8 p0 = *(const u16x8*)pr;
      u16x8 p1 = *(const u16x8*)(pr + 8);
      uint32_t ou0 = 0, ou1 = 0, ou2 = 0, ou3 = 0;
      #pragma unroll
      for (int j = 0; j < 4; ++j) {
        int a0 = (int)(b2f(p0[j]) * 24.f + 0.5f);     a0 = a0 > 255 ? 255 : a0;
        int a1 = (int)(b2f(p0[4 + j]) * 24.f + 0.5f); a1 = a1 > 255 ? 255 : a1;
        int a2 = (int)(b2f(p1[j]) * 24.f + 0.5f);     a2 = a2 > 255 ? 255 : a2;
        int a3 = (int)(b2f(p1[4 + j]) * 24.f + 0.5f); a3 = a3 > 255 ? 255 : a3;
        ou0 |= (uint32_t)a0 << (8 * j);
        ou1 |= (uint32_t)a1 << (8 * j);
        ou2 |= (uint32_t)a2 << (8 * j);
        ou3 |= (uint32_t)a3 << (8 * j);
      }
      uint4 ov; ov.x = ou0; ov.y = ou1; ov.z = ou2; ov.w = ou3;
      *(uint4*)(pscr + ((size_t)pi * TT + row0 + (lane >> 2)) * TT +
                (size_t)s * KB2 + (lane & 3) * 16) = ov;
    }
    __syncthreads();
  }

  #pragma unroll
  for (int r = 0; r < 4; ++r) {
    float sv = ssum[r];
    sv += __shfl_xor(sv, 1);
    sv += __shfl_xor(sv, 2);
    sv += __shfl_xor(sv, 4);
    sv += __shfl_xor(sv, 8);
    float inv = 1.f / sv;
    if (l15 == 0) sums[(size_t)bh * TT + row0 + g * 4 + r] = inv;
    #pragma unroll
    for (int n = 0; n < 4; ++n) o[n][r] *= inv;
  }
  #pragma unroll
  for (int r = 0; r < 4; ++r) {
    size_t arow = (size_t)(b * TT + row0 + g * 4 + r) * DMODEL + h * HD;
    #pragma unroll
    for (int n = 0; n < 4; ++n)
      ao[arow + n * 16 + l15] = f2b(o[n][r]);
  }
}

// ---------------- head-average from u8 scratch ----------------
__global__ __launch_bounds__(256)
void k_avg(const unsigned char* __restrict__ pscr, const float* __restrict__ sums,
           float* __restrict__ avg, int b0, int plocal) {
  const int i = blockIdx.x, b = b0 + blockIdx.y;
  const int j0 = threadIdx.x * 8;
  float acc[8] = {};
  #pragma unroll
  for (int hh = 0; hh < 8; ++hh) {
    float inv = sums[(size_t)(b * 8 + hh) * TT + i];
    int pi = plocal ? hh : (b * 8 + hh);
    uint2 p = *(const uint2*)(pscr + ((size_t)pi * TT + i) * TT + j0);
    #pragma unroll
    for (int jj = 0; jj < 4; ++jj) {
      acc[jj]     += (float)((p.x >> (8 * jj)) & 255u) * inv;
      acc[4 + jj] += (float)((p.y >> (8 * jj)) & 255u) * inv;
    }
  }
  const float sc = 1.f / (24.f * 8.f);
  float4 q0 = {acc[0] * sc, acc[1] * sc, acc[2] * sc, acc[3] * sc};
  float4 q1 = {acc[4] * sc, acc[5] * sc, acc[6] * sc, acc[7] * sc};
  float* op = avg + ((size_t)(b * TT + i)) * TT + j0;
  *(float4*)op = q0;
  *(float4*)(op + 4) = q1;
}

// ---------------- two-pass attention with in-LDS avg (fallback only) ----------------
#define KS 32
#define NSTEP (TT / KS)

__device__ __forceinline__ void loadK(const unsigned short* src, u16x8* kr) {
  int row = threadIdx.x >> 4, c0 = (threadIdx.x & 15) * 8;
  const unsigned short* p = src + row * 512 + c0;
  #pragma unroll
  for (int j = 0; j < 4; ++j) kr[j] = *(const u16x8*)(p + j * 128);
}
__device__ __forceinline__ void writeK(unsigned short* Kt, const u16x8* kr) {
  int row = threadIdx.x >> 4, c0 = (threadIdx.x & 15) * 8, sw = (row & 7) << 3;
  #pragma unroll
  for (int j = 0; j < 4; ++j)
    *(u16x8*)(Kt + row * 512 + ((c0 + j * 128) ^ sw)) = kr[j];
}
__device__ __forceinline__ void loadV(const unsigned short* vt_b, int s0, u16x8* vr) {
  const unsigned short* p = vt_b + (size_t)threadIdx.x * TT + s0;
  #pragma unroll
  for (int j = 0; j < 4; ++j) vr[j] = *(const u16x8*)(p + j * 8);
}
__device__ __forceinline__ void writeV(unsigned short* Vt, const u16x8* vr) {
  int row = threadIdx.x, sw = ((row >> 1) & 3) << 3;
  #pragma unroll
  for (int j = 0; j < 4; ++j)
    *(u16x8*)(Vt + row * 32 + ((j * 8) ^ sw)) = vr[j];
}

__global__ __launch_bounds__(512)
void k_attn(const unsigned short* __restrict__ q, const unsigned short* __restrict__ kk,
            const unsigned short* __restrict__ vt, unsigned short* __restrict__ ao,
            float* __restrict__ avg) {
  __shared__ __align__(16) unsigned short Kt[2][KS * 512];
  __shared__ __align__(16) unsigned short Vt[2][512 * KS];
  __shared__ __align__(16) unsigned short Pb[2][NH][16][40];
  const int tid  = threadIdx.x;
  const int lane = tid & 63;
  const int w    = tid >> 6;
  const int l15  = lane & 15;
  const int g    = lane >> 4;
  const int qt   = blockIdx.x;
  const int b    = blockIdx.y;

  const unsigned short* kbase = kk + (size_t)(b * TT) * DMODEL;
  const unsigned short* vbase = vt + (size_t)b * DMODEL * TT;

  const size_t qoff = (size_t)(b * TT + qt * 16 + l15) * DMODEL + w * HD + g * 8;
  const bf16x8 aq0 = *(const bf16x8*)(q + qoff);
  const bf16x8 aq1 = *(const bf16x8*)(q + qoff + 32);

  u16x8 kr[4], vr[4];

  float ssum[4] = {0.f, 0.f, 0.f, 0.f};
  loadK(kbase, kr);
  writeK(Kt[0], kr);
  __syncthreads();
  for (int s = 0; s < NSTEP; ++s) {
    const int cur = s & 1;
    if (s < NSTEP - 1) loadK(kbase + (size_t)(s + 1) * KS * 512, kr);
    f32x4 sf[2] = {};
    #pragma unroll
    for (int n = 0; n < 2; ++n) {
      const int row = n * 16 + l15, sw = (row & 7) << 3;
      const unsigned short* kp = Kt[cur] + row * 512;
      bf16x8 b0 = *(const bf16x8*)(kp + ((w * 64 + g * 8) ^ sw));
      bf16x8 b1 = *(const bf16x8*)(kp + ((w * 64 + 32 + g * 8) ^ sw));
      sf[n] = mfma16(aq0, b0, sf[n]);
      sf[n] = mfma16(aq1, b1, sf[n]);
    }
    #pragma unroll
    for (int r = 0; r < 4; ++r)
      ssum[r] += __expf(sf[0][r] * 0.125f) + __expf(sf[1][r] * 0.125f);
    if (s < NSTEP - 1) writeK(Kt[cur ^ 1], kr);
    __syncthreads();
  }
  float inv_s[4];
  #pragma unroll
  for (int r = 0; r < 4; ++r) {
    float v = ssum[r];
    v += __shfl_xor(v, 1);
    v += __shfl_xor(v, 2);
    v += __shfl_xor(v, 4);
    v += __shfl_xor(v, 8);
    inv_s[r] = 1.f / v;
  }

  f32x4 o[4] = {};
  loadK(kbase, kr);
  loadV(vbase, 0, vr);
  writeK(Kt[0], kr);
  writeV(Vt[0], vr);
  __syncthreads();
  for (int s = 0; s < NSTEP; ++s) {
    const int cur = s & 1;
    if (s < NSTEP - 1) {
      loadK(kbase + (size_t)(s + 1) * KS * 512, kr);
      loadV(vbase, (s + 1) * KS, vr);
    }
    f32x4 sf[2] = {};
    #pragma unroll
    for (int n = 0; n < 2; ++n) {
      const int row = n * 16 + l15, sw = (row & 7) << 3;
      const unsigned short* kp = Kt[cur] + row * 512;
      bf16x8 b0 = *(const bf16x8*)(kp + ((w * 64 + g * 8) ^ sw));
      bf16x8 b1 = *(const bf16x8*)(kp + ((w * 64 + 32 + g * 8) ^ sw));
      sf[n] = mfma16(aq0, b0, sf[n]);
      sf[n] = mfma16(aq1, b1, sf[n]);
    }
    #pragma unroll
    for (int n = 0; n < 2; ++n)
      #pragma unroll
      for (int r = 0; r < 4; ++r)
        Pb[cur][w][g * 4 + r][n * 16 + l15] = f2b(__expf(sf[n][r] * 0.125f) * inv_s[r]);
    __syncthreads();

    bf16x8 pa = *(const bf16x8*)&Pb[cur][w][l15][g * 8];
    #pragma unroll
    for (int n = 0; n < 4; ++n) {
      const int row = w * 64 + n * 16 + l15;
      bf16x8 bv = *(const bf16x8*)(Vt[cur] + row * 32 + ((g * 8) ^ (((row >> 1) & 3) << 3)));
      o[n] = mfma16(pa, bv, o[n]);
    }
    {
      int i = tid >> 5, j = tid & 31;
      float sm = 0.f;
      #pragma unroll
      for (int hh = 0; hh < NH; ++hh) sm += b2f(Pb[cur][hh][i][j]);
      avg[(size_t)(b * TT + qt * 16 + i) * TT + s * KS + j] = sm * 0.125f;
    }
    if (s < NSTEP - 1) {
      writeK(Kt[cur ^ 1], kr);
      writeV(Vt[cur ^ 1], vr);
    }
    __syncthreads();
  }

  #pragma unroll
  for (int n = 0; n < 4; ++n)
    #pragma unroll
    for (int r = 0; r < 4; ++r)
      ao[(size_t)(b * TT + qt * 16 + g * 4 + r) * DMODEL + w * HD + n * 16 + l15] = f2b(o[n][r]);
}

// ---------------- final mean over T ----------------
__global__ void k_mean(const float* __restrict__ hf, float* __restrict__ out) {
  int c = blockIdx.x * 256 + threadIdx.x;
  int b = blockIdx.y;
  int t0 = blockIdx.z * 128;
  float s = 0.f;
  for (int t = 0; t < 128; ++t)
    s += hf[(size_t)(b * TT + t0 + t) * DMODEL + c];
  atomicAdd(&out[b * DMODEL + c], s * (1.f / TT));
}

extern "C" void kernel_launch(void* const* d_in, const int* in_sizes, int n_in,
                              void* d_out, int out_size, void* d_ws, size_t ws_size,
                              hipStream_t stream) {
  const int*   x    = (const int*)d_in[0];
  const float* emb  = (const float*)d_in[1];
  const float* pos  = (const float*)d_in[2];
  const float* Wq   = (const float*)d_in[3];
  const float* bq   = (const float*)d_in[4];
  const float* Wk   = (const float*)d_in[5];
  const float* bk   = (const float*)d_in[6];
  const float* Wv   = (const float*)d_in[7];
  const float* bv   = (const float*)d_in[8];
  const float* Wo   = (const float*)d_in[9];
  const float* bo   = (const float*)d_in[10];
  const float* W1   = (const float*)d_in[11];
  const float* b1   = (const float*)d_in[12];
  const float* W2   = (const float*)d_in[13];
  const float* b2   = (const float*)d_in[14];
  const float* ln1g = (const float*)d_in[15];
  const float* ln1b = (const float*)d_in[16];
  const float* ln2g = (const float*)d_in[17];
  const float* ln2b = (const float*)d_in[18];
  const float* lnfg = (const float*)d_in[19];
  const float* lnfb = (const float*)d_in[20];

  char* w = (char*)d_ws;
  const size_t MB = 1024 * 1024;
  unsigned short* wqb = (unsigned short*)(w + 0 * MB);
  unsigned short* wkb = (unsigned short*)(w + 2 * MB);
  unsigned short* wvb = (unsigned short*)(w + 4 * MB);
  unsigned short* wob = (unsigned short*)(w + 6 * MB);
  unsigned short* w1b = (unsigned short*)(w + 8 * MB);
  unsigned short* w2b = (unsigned short*)(w + 16 * MB);
  float*          h   = (float*)(w + 24 * MB);
  unsigned short* hn  = (unsigned short*)(w + 32 * MB);
  unsigned short* qb  = (unsigned short*)(w + 36 * MB);
  unsigned short* kb  = (unsigned short*)(w + 40 * MB);
  unsigned short* vb  = (unsigned short*)(w + 44 * MB);
  unsigned short* vtb = (unsigned short*)(w + 48 * MB);
  unsigned short* ab  = (unsigned short*)(w + 52 * MB);
  unsigned short* ff  = (unsigned short*)(w + 56 * MB);   // 16 MB
  float*          sums = (float*)(w + 72 * MB);           // 128 KB
  unsigned char*  pscr_ws = (unsigned char*)(w + 73 * MB);
  float*          hf  = (float*)(w + 36 * MB);            // reuse q space after layers

  k_f2b<<<1024, 256, 0, stream>>>(Wq, wqb, 262144);
  k_f2b<<<1024, 256, 0, stream>>>(Wk, wkb, 262144);
  k_f2b<<<1024, 256, 0, stream>>>(Wv, wvb, 262144);
  k_f2b<<<1024, 256, 0, stream>>>(Wo, wob, 262144);
  k_f2b<<<4096, 256, 0, stream>>>(W1, w1b, 1048576);
  k_f2b<<<4096, 256, 0, stream>>>(W2, w2b, 1048576);

  k_embed<<<BB * TT, 128, 0, stream>>>(x, emb, pos, h);

  float* attn_maps = (float*)d_out + 1024;
  const size_t RSZ = (size_t)BB * TT * TT;               // floats per map region (32 MiB)
  const size_t NEED_FULL = 73 * MB + 64 * MB;
  const size_t NEED_HALF = 73 * MB + 32 * MB;

  for (int l = 0; l < 4; ++l) {
    k_ln<1><<<BB * TT / 4, 256, 0, stream>>>(h, ln1g + l * DMODEL, ln1b + l * DMODEL, hn);
    dim3 gq(DMODEL / 128, BB * TT / 128, 3);
    k_gemm_qkv<<<gq, 256, 0, stream>>>(hn,
        wqb + (size_t)l * DMODEL * DMODEL, wkb + (size_t)l * DMODEL * DMODEL,
        wvb + (size_t)l * DMODEL * DMODEL,
        bq + l * DMODEL, bk + l * DMODEL, bv + l * DMODEL, qb, kb, vb);
    k_trans<<<dim3(TT / 64, BB * NH), 256, 0, stream>>>(vb, vtb);

    float* maps_l = attn_maps + (size_t)l * RSZ;
    if (l <= 1) {
      unsigned char* ps = (unsigned char*)(attn_maps + (size_t)(l + 1) * RSZ);
      k_attn1<<<dim3(TT / 64, BB * NH), 256, 0, stream>>>(qb, kb, vtb, ab, ps, sums, 0, 0);
      k_avg<<<dim3(TT, BB), 256, 0, stream>>>(ps, sums, maps_l, 0, 0);
    } else if (l == 2) {
      unsigned char* ps = (unsigned char*)(attn_maps + (size_t)3 * RSZ);
      for (int b = 0; b < BB; ++b) {
        k_attn1<<<dim3(TT / 64, NH), 256, 0, stream>>>(qb, kb, vtb, ab, ps, sums, b * NH, 1);
        k_avg<<<dim3(TT, 1), 256, 0, stream>>>(ps, sums, maps_l, b, 1);
      }
    } else {
      if (ws_size >= NEED_FULL) {
        k_attn1<<<dim3(TT / 64, BB * NH), 256, 0, stream>>>(qb, kb, vtb, ab, pscr_ws, sums, 0, 0);
        k_avg<<<dim3(TT, BB), 256, 0, stream>>>(pscr_ws, sums, maps_l, 0, 0);
      } else if (ws_size >= NEED_HALF) {
        for (int b = 0; b < BB; ++b) {
          k_attn1<<<dim3(TT / 64, NH), 256, 0, stream>>>(qb, kb, vtb, ab, pscr_ws, sums, b * NH, 1);
          k_avg<<<dim3(TT, 1), 256, 0, stream>>>(pscr_ws, sums, maps_l, b, 1);
        }
      } else {
        k_attn<<<dim3(TT / 16, BB), 512, 0, stream>>>(qb, kb, vtb, ab, maps_l);
      }
    }

    k_gemm<0, 1, 0><<<dim3(DMODEL / 128, BB * TT / 128), 256, 0, stream>>>(ab,
        wob + (size_t)l * DMODEL * DMODEL, bo + l * DMODEL, h, nullptr, h, 4096, 512, 512);
    k_ln<1><<<BB * TT / 4, 256, 0, stream>>>(h, ln2g + l * DMODEL, ln2b + l * DMODEL, hn);
    k_gemm<1, 0, 1><<<dim3(DFF / 128, BB * TT / 128), 256, 0, stream>>>(hn,
        w1b + (size_t)l * DFF * DMODEL, b1 + l * DFF, nullptr, ff, nullptr, 4096, 2048, 512);
    k_gemm<0, 1, 0><<<dim3(DMODEL / 128, BB * TT / 128), 256, 0, stream>>>(ff,
        w2b + (size_t)l * DMODEL * DFF, b2 + l * DMODEL, h, nullptr, h, 4096, 512, 2048);
  }
  k_ln<0><<<BB * TT / 4, 256, 0, stream>>>(h, lnfg, lnfb, hf);
  hipMemsetAsync(d_out, 0, 1024 * sizeof(float), stream);
  k_mean<<<dim3(2, BB, 16), 256, 0, stream>>>(hf, (float*)d_out);
}

// Round 7
// 965.259 us; speedup vs baseline: 1.4269x; 1.1188x over previous
//
#include <hip/hip_runtime.h>
#include <stdint.h>

using bf16x8 = __attribute__((ext_vector_type(8))) __bf16;
using u16x8  = __attribute__((ext_vector_type(8))) unsigned short;
using f32x4  = __attribute__((ext_vector_type(4))) float;

#define DMODEL 512
#define DFF    2048
#define TT     2048
#define BB     2
#define NH     8
#define HD     64

__device__ __forceinline__ unsigned short f2b(float f) {
  union { float f; uint32_t u; } c; c.f = f;
  uint32_t u = c.u;
  uint32_t r = (u + 0x7FFFu + ((u >> 16) & 1u)) >> 16;
  return (unsigned short)r;
}
__device__ __forceinline__ float b2f(unsigned short s) {
  union { uint32_t u; float f; } c; c.u = ((uint32_t)s) << 16;
  return c.f;
}
__device__ __forceinline__ bf16x8 asbf(u16x8 x) { return __builtin_bit_cast(bf16x8, x); }

__device__ __forceinline__ f32x4 mfma16(bf16x8 a, bf16x8 b, f32x4 c) {
  return __builtin_amdgcn_mfma_f32_16x16x32_bf16(a, b, c, 0, 0, 0);
}

__device__ __forceinline__ void gload16(const void* g, void* l) {
  __builtin_amdgcn_global_load_lds((__attribute__((address_space(1))) void*)(g),
                                   (__attribute__((address_space(3))) void*)(l),
                                   16, 0, 0);
}

// ---------------- f32 -> bf16 convert (all 6 weight stacks, one launch) -------------
__global__ void k_f2b_all(const float* w0, const float* w1, const float* w2,
                          const float* w3, const float* w4, const float* w5,
                          unsigned short* o0, unsigned short* o1, unsigned short* o2,
                          unsigned short* o3, unsigned short* o4, unsigned short* o5) {
  const int z = blockIdx.y;
  const float* in; unsigned short* out; int n4;
  if      (z == 0) { in = w0; out = o0; n4 = 262144; }
  else if (z == 1) { in = w1; out = o1; n4 = 262144; }
  else if (z == 2) { in = w2; out = o2; n4 = 262144; }
  else if (z == 3) { in = w3; out = o3; n4 = 262144; }
  else if (z == 4) { in = w4; out = o4; n4 = 1048576; }
  else             { in = w5; out = o5; n4 = 1048576; }
  int i = blockIdx.x * blockDim.x + threadIdx.x;
  if (i < n4) {
    float4 v = ((const float4*)in)[i];
    ushort4 o;
    o.x = f2b(v.x); o.y = f2b(v.y); o.z = f2b(v.z); o.w = f2b(v.w);
    ((ushort4*)out)[i] = o;
  }
}

// ---------------- embedding + positional ----------------
__global__ void k_embed(const int* __restrict__ x, const float* __restrict__ emb,
                        const float* __restrict__ pos, float* __restrict__ h) {
  int row = blockIdx.x;            // b*T + t
  int t = row & (TT - 1);
  int c = threadIdx.x * 4;
  int idx = x[row];
  float4 e = *(const float4*)(emb + (size_t)idx * DMODEL + c);
  float4 p = *(const float4*)(pos + (size_t)t * DMODEL + c);
  e.x += p.x; e.y += p.y; e.z += p.z; e.w += p.w;
  *(float4*)(h + (size_t)row * DMODEL + c) = e;
}

// ---------------- layernorm (one wave per 512-row) ----------------
template<int BF16OUT>
__global__ void k_ln(const float* __restrict__ in, const float* __restrict__ gam,
                     const float* __restrict__ bet, void* __restrict__ out) {
  int wid  = threadIdx.x >> 6;
  int lane = threadIdx.x & 63;
  int row  = blockIdx.x * 4 + wid;
  const float* p = in + (size_t)row * DMODEL + lane * 8;
  float4 v0 = *(const float4*)p;
  float4 v1 = *(const float4*)(p + 4);
  float vals[8] = {v0.x, v0.y, v0.z, v0.w, v1.x, v1.y, v1.z, v1.w};
  float s = 0.f;
  #pragma unroll
  for (int j = 0; j < 8; ++j) s += vals[j];
  #pragma unroll
  for (int m = 1; m < 64; m <<= 1) s += __shfl_xor(s, m);
  float mean = s * (1.f / DMODEL);
  float vsum = 0.f;
  #pragma unroll
  for (int j = 0; j < 8; ++j) { vals[j] -= mean; vsum += vals[j] * vals[j]; }
  #pragma unroll
  for (int m = 1; m < 64; m <<= 1) vsum += __shfl_xor(vsum, m);
  float inv = rsqrtf(vsum * (1.f / DMODEL) + 1e-5f);
  const float* gp = gam + lane * 8;
  const float* bp = bet + lane * 8;
  float4 g0 = *(const float4*)gp, g1 = *(const float4*)(gp + 4);
  float4 b0 = *(const float4*)bp, b1 = *(const float4*)(bp + 4);
  float gs[8] = {g0.x, g0.y, g0.z, g0.w, g1.x, g1.y, g1.z, g1.w};
  float bs[8] = {b0.x, b0.y, b0.z, b0.w, b1.x, b1.y, b1.z, b1.w};
  float ov[8];
  #pragma unroll
  for (int j = 0; j < 8; ++j) ov[j] = vals[j] * inv * gs[j] + bs[j];
  if (BF16OUT) {
    u16x8 o;
    #pragma unroll
    for (int j = 0; j < 8; ++j) o[j] = f2b(ov[j]);
    *(u16x8*)((unsigned short*)out + (size_t)row * DMODEL + lane * 8) = o;
  } else {
    float4 o0 = {ov[0], ov[1], ov[2], ov[3]};
    float4 o1 = {ov[4], ov[5], ov[6], ov[7]};
    float* q = (float*)out + (size_t)row * DMODEL + lane * 8;
    *(float4*)q = o0;
    *(float4*)(q + 4) = o1;
  }
}

// ---------------- bf16 MFMA GEMM (128x128): C = A[M,K] * W[N,K]^T + bias ------------
// vtrans: instead of outb, write V^T layout vt[(b*8+h)*64+d][t] (uniform branch).
template<int RELU, int RESID, int OUTBF>
__device__ __forceinline__ void gemm_body(
    const unsigned short* __restrict__ A, const unsigned short* __restrict__ W,
    const float* __restrict__ bias, const float* resid,
    unsigned short* outb, float* outf, int M, int N, int K,
    unsigned short* vtout, int vtrans) {
  __shared__ __align__(16) unsigned short lsA[128 * 64];
  __shared__ __align__(16) unsigned short lsB[128 * 64];
  const int tid  = threadIdx.x;
  const int lane = tid & 63;
  const int wid  = tid >> 6;
  const int wr = wid >> 1, wc = wid & 1;
  const int l15 = lane & 15, g = lane >> 4;
  const int row0 = blockIdx.y * 128, col0 = blockIdx.x * 128;
  f32x4 acc[4][4] = {};
  for (int k0 = 0; k0 < K; k0 += 64) {
    #pragma unroll
    for (int p = 0; p < 4; ++p) {
      int s = p * 256 + tid;
      int r = s >> 3, seg = s & 7;
      gload16(A + (size_t)(row0 + r) * K + k0 + seg * 8, lsA + s * 8);
      gload16(W + (size_t)(col0 + r) * K + k0 + seg * 8, lsB + s * 8);
    }
    __syncthreads();
    #pragma unroll
    for (int ks = 0; ks < 2; ++ks) {
      bf16x8 af[4], bf[4];
      #pragma unroll
      for (int m = 0; m < 4; ++m)
        af[m] = *(const bf16x8*)&lsA[(wr * 64 + m * 16 + l15) * 64 + ks * 32 + g * 8];
      #pragma unroll
      for (int n = 0; n < 4; ++n)
        bf[n] = *(const bf16x8*)&lsB[(wc * 64 + n * 16 + l15) * 64 + ks * 32 + g * 8];
      #pragma unroll
      for (int m = 0; m < 4; ++m)
        #pragma unroll
        for (int n = 0; n < 4; ++n)
          acc[m][n] = mfma16(af[m], bf[n], acc[m][n]);
    }
    __syncthreads();
  }
  if (vtrans) {
    // write transposed per-head: vt[(b*8+h)*64+d][t], 4 tokens packed per store
    #pragma unroll
    for (int m = 0; m < 4; ++m) {
      const int grow = row0 + wr * 64 + m * 16 + g * 4;
      const int t = grow & (TT - 1), bb = grow >> 11;
      #pragma unroll
      for (int n = 0; n < 4; ++n) {
        const int gcol = col0 + wc * 64 + n * 16 + l15;
        const float bv = bias[gcol];
        const int hh = gcol >> 6, dd = gcol & 63;
        ushort4 pk;
        pk.x = f2b(acc[m][n][0] + bv);
        pk.y = f2b(acc[m][n][1] + bv);
        pk.z = f2b(acc[m][n][2] + bv);
        pk.w = f2b(acc[m][n][3] + bv);
        *(ushort4*)(vtout + ((size_t)((bb * 8 + hh) * HD + dd)) * TT + t) = pk;
      }
    }
    return;
  }
  #pragma unroll
  for (int m = 0; m < 4; ++m) {
    const int grow = row0 + wr * 64 + m * 16 + g * 4;
    #pragma unroll
    for (int n = 0; n < 4; ++n) {
      const int gcol = col0 + wc * 64 + n * 16 + l15;
      const float bv = bias[gcol];
      #pragma unroll
      for (int r = 0; r < 4; ++r) {
        float v = acc[m][n][r] + bv;
        if (RESID) v += resid[(size_t)(grow + r) * N + gcol];
        if (RELU)  v = v > 0.f ? v : 0.f;
        if (OUTBF) outb[(size_t)(grow + r) * N + gcol] = f2b(v);
        else       outf[(size_t)(grow + r) * N + gcol] = v;
      }
    }
  }
}

template<int RELU, int RESID, int OUTBF>
__global__ __launch_bounds__(256)
void k_gemm(const unsigned short* __restrict__ A, const unsigned short* __restrict__ W,
            const float* __restrict__ bias, const float* resid,
            unsigned short* outb, float* outf, int M, int N, int K) {
  gemm_body<RELU, RESID, OUTBF>(A, W, bias, resid, outb, outf, M, N, K, nullptr, 0);
}

__global__ __launch_bounds__(256)
void k_gemm_qkv(const unsigned short* __restrict__ A,
                const unsigned short* Wq, const unsigned short* Wk, const unsigned short* Wv,
                const float* bq, const float* bk, const float* bv,
                unsigned short* q, unsigned short* k, unsigned short* vtout) {
  if (blockIdx.z == 0)
    gemm_body<0, 0, 1>(A, Wq, bq, nullptr, q, nullptr, 4096, 512, 512, nullptr, 0);
  else if (blockIdx.z == 1)
    gemm_body<0, 0, 1>(A, Wk, bk, nullptr, k, nullptr, 4096, 512, 512, nullptr, 0);
  else
    gemm_body<0, 0, 1>(A, Wv, bv, nullptr, nullptr, nullptr, 4096, 512, 512, vtout, 1);
}

// ---------------- bf16 MFMA GEMM (64x128): for N=512 outputs (grid 4x64=256) --------
template<int RELU, int RESID, int OUTBF>
__global__ __launch_bounds__(256)
void k_gemm_bm64(const unsigned short* __restrict__ A, const unsigned short* __restrict__ W,
                 const float* __restrict__ bias, const float* resid,
                 unsigned short* outb, float* outf, int M, int N, int K) {
  __shared__ __align__(16) unsigned short lsA[64 * 64];
  __shared__ __align__(16) unsigned short lsB[128 * 64];
  const int tid  = threadIdx.x;
  const int lane = tid & 63;
  const int wc   = tid >> 6;            // wave = column quadrant
  const int l15 = lane & 15, g = lane >> 4;
  const int row0 = blockIdx.y * 64, col0 = blockIdx.x * 128;
  f32x4 acc[4][2] = {};
  for (int k0 = 0; k0 < K; k0 += 64) {
    #pragma unroll
    for (int p = 0; p < 2; ++p) {
      int s = p * 256 + tid;
      int r = s >> 3, seg = s & 7;
      gload16(A + (size_t)(row0 + r) * K + k0 + seg * 8, lsA + s * 8);
    }
    #pragma unroll
    for (int p = 0; p < 4; ++p) {
      int s = p * 256 + tid;
      int r = s >> 3, seg = s & 7;
      gload16(W + (size_t)(col0 + r) * K + k0 + seg * 8, lsB + s * 8);
    }
    __syncthreads();
    #pragma unroll
    for (int ks = 0; ks < 2; ++ks) {
      bf16x8 af[4], bf[2];
      #pragma unroll
      for (int m = 0; m < 4; ++m)
        af[m] = *(const bf16x8*)&lsA[(m * 16 + l15) * 64 + ks * 32 + g * 8];
      #pragma unroll
      for (int n = 0; n < 2; ++n)
        bf[n] = *(const bf16x8*)&lsB[(wc * 32 + n * 16 + l15) * 64 + ks * 32 + g * 8];
      #pragma unroll
      for (int m = 0; m < 4; ++m)
        #pragma unroll
        for (int n = 0; n < 2; ++n)
          acc[m][n] = mfma16(af[m], bf[n], acc[m][n]);
    }
    __syncthreads();
  }
  #pragma unroll
  for (int m = 0; m < 4; ++m) {
    const int grow = row0 + m * 16 + g * 4;
    #pragma unroll
    for (int n = 0; n < 2; ++n) {
      const int gcol = col0 + wc * 32 + n * 16 + l15;
      const float bv = bias[gcol];
      #pragma unroll
      for (int r = 0; r < 4; ++r) {
        float v = acc[m][n][r] + bv;
        if (RESID) v += resid[(size_t)(grow + r) * N + gcol];
        if (RELU)  v = v > 0.f ? v : 0.f;
        if (OUTBF) outb[(size_t)(grow + r) * N + gcol] = f2b(v);
        else       outf[(size_t)(grow + r) * N + gcol] = v;
      }
    }
  }
}

// ---------------- single-pass attention, swapped-QK^T, gload_lds staged -------------
// block = 4 waves x 64 q-rows x 1 head; grid (T/64, nbh) = 512 blocks.
// S^T = mfma(K, Q): lane holds 4 consecutive keys per 16-block -> packed b64 P writes.
// K/V staged via global_load_lds with pre-swizzled per-lane source addresses.
#define KB2 64
#define NST2 (TT / KB2)

__global__ __launch_bounds__(256)
void k_attn1(const unsigned short* __restrict__ q, const unsigned short* __restrict__ kk,
             const unsigned short* __restrict__ vt, unsigned short* __restrict__ ao,
             unsigned char* __restrict__ pscr, float* __restrict__ sums,
             int bh0, int plocal) {
  __shared__ __align__(16) unsigned short Kt[2][KB2 * 64];   // 8KB each, swizzled rows
  __shared__ __align__(16) unsigned short Vt[2][KB2 * 64];   // 8KB each, swizzled rows
  __shared__ __align__(16) unsigned short Ps[4][16][76];     // per-wave P bf16
  __shared__ __align__(16) unsigned char  Pu[4][16][80];     // per-wave P u8
  const int tid  = threadIdx.x;
  const int lane = tid & 63;
  const int w    = tid >> 6;
  const int l15  = lane & 15;
  const int g    = lane >> 4;
  const int qt   = blockIdx.x;
  const int bh   = bh0 + blockIdx.y;
  const int b    = bh >> 3, h = bh & 7;
  const int pi   = plocal ? (int)blockIdx.y : bh;
  const int row0 = qt * 64 + w * 16;

  const unsigned short* kgp = kk + (size_t)(b * TT) * DMODEL + h * HD;
  const unsigned short* vgp = vt + (size_t)(bh * HD) * TT;

  // staging geometry: pass p covers rows 32p.. ; s = p*256+tid; row=s>>3; col=(s&7)*16B
  const int s0i = tid, s1i = 256 + tid;
  const int r0 = s0i >> 3, r1 = s1i >> 3;
  const int kc0 = (((s0i & 7) * 16) ^ ((r0 & 7) << 4)) >> 1;   // u16 offset, pre-swizzled
  const int kc1 = (((s1i & 7) * 16) ^ ((r1 & 7) << 4)) >> 1;

  const size_t qoff = (size_t)(b * TT + row0 + l15) * DMODEL + h * HD + g * 8;
  const bf16x8 aq0 = *(const bf16x8*)(q + qoff);
  const bf16x8 aq1 = *(const bf16x8*)(q + qoff + 32);

  f32x4 o[4] = {};
  float ssum = 0.f;

  // prologue: stage step 0
  gload16(kgp + (size_t)r0 * DMODEL + kc0, (unsigned short*)Kt[0] + s0i * 8);
  gload16(kgp + (size_t)r1 * DMODEL + kc1, (unsigned short*)Kt[0] + s1i * 8);
  gload16(vgp + (size_t)r0 * TT + kc0,     (unsigned short*)Vt[0] + s0i * 8);
  gload16(vgp + (size_t)r1 * TT + kc1,     (unsigned short*)Vt[0] + s1i * 8);
  __syncthreads();

  for (int s = 0; s < NST2; ++s) {
    const int cur = s & 1;
    if (s + 1 < NST2) {
      const size_t ko = (size_t)(s + 1) * KB2;
      gload16(kgp + (ko + r0) * DMODEL + kc0, (unsigned short*)Kt[cur ^ 1] + s0i * 8);
      gload16(kgp + (ko + r1) * DMODEL + kc1, (unsigned short*)Kt[cur ^ 1] + s1i * 8);
      gload16(vgp + (size_t)r0 * TT + ko + kc0, (unsigned short*)Vt[cur ^ 1] + s0i * 8);
      gload16(vgp + (size_t)r1 * TT + ko + kc1, (unsigned short*)Vt[cur ^ 1] + s1i * 8);
    }

    // S^T: sf[n][r] = S[q=row0+l15][key = s*64 + n*16 + g*4 + r]
    f32x4 sf[4];
    #pragma unroll
    for (int n = 0; n < 4; ++n) {
      const int kr = n * 16 + l15, ksw = (kr & 7) << 3;
      const unsigned short* kp = &Kt[cur][kr * 64];
      f32x4 c = {};
      c = mfma16(*(const bf16x8*)(kp + ((g * 8) ^ ksw)), aq0, c);
      c = mfma16(*(const bf16x8*)(kp + ((32 + g * 8) ^ ksw)), aq1, c);
      sf[n] = c;
    }
    // exp + packed P writes (bf16 b64 + u8 b32), scalar row-sum
    #pragma unroll
    for (int n = 0; n < 4; ++n) {
      float e0 = __expf(sf[n][0] * 0.125f);
      float e1 = __expf(sf[n][1] * 0.125f);
      float e2 = __expf(sf[n][2] * 0.125f);
      float e3 = __expf(sf[n][3] * 0.125f);
      ssum += (e0 + e1) + (e2 + e3);
      ushort4 pk;
      pk.x = f2b(e0); pk.y = f2b(e1); pk.z = f2b(e2); pk.w = f2b(e3);
      *(ushort4*)&Ps[w][l15][n * 16 + g * 4] = pk;
      int a0 = (int)(e0 * 24.f + 0.5f); a0 = a0 > 255 ? 255 : a0;
      int a1 = (int)(e1 * 24.f + 0.5f); a1 = a1 > 255 ? 255 : a1;
      int a2 = (int)(e2 * 24.f + 0.5f); a2 = a2 > 255 ? 255 : a2;
      int a3 = (int)(e3 * 24.f + 0.5f); a3 = a3 > 255 ? 255 : a3;
      *(uint32_t*)&Pu[w][l15][n * 16 + g * 4] =
          (uint32_t)a0 | ((uint32_t)a1 << 8) | ((uint32_t)a2 << 16) | ((uint32_t)a3 << 24);
    }
    // PV: A = P[q=l15][keys], B = V^T[d][keys]
    #pragma unroll
    for (int kc = 0; kc < 2; ++kc) {
      bf16x8 pa = *(const bf16x8*)&Ps[w][l15][kc * 32 + g * 8];
      #pragma unroll
      for (int n = 0; n < 4; ++n) {
        const int dr = n * 16 + l15, vsw = (dr & 7) << 3;
        bf16x8 bv = *(const bf16x8*)(&Vt[cur][dr * 64] + ((kc * 32 + g * 8) ^ vsw));
        o[n] = mfma16(pa, bv, o[n]);
      }
    }
    // pscr coalesced u8 store (16B/lane)
    {
      const int qq = lane >> 2, ch = lane & 3;
      uint4 pv = *(const uint4*)&Pu[w][qq][ch * 16];
      *(uint4*)(pscr + ((size_t)pi * TT + row0 + qq) * TT + (size_t)s * KB2 + ch * 16) = pv;
    }
    __syncthreads();
  }

  // row-sum reduce across g-groups (q = row0 + l15)
  float sv = ssum;
  sv += __shfl_xor(sv, 16);
  sv += __shfl_xor(sv, 32);
  float inv = 1.f / sv;
  if (lane < 16) sums[(size_t)bh * TT + row0 + l15] = inv;

  // scale O rows (q = row0 + g*4 + r) and store
  #pragma unroll
  for (int r = 0; r < 4; ++r) {
    float invq = __shfl(inv, g * 4 + r);
    size_t arow = (size_t)(b * TT + row0 + g * 4 + r) * DMODEL + h * HD;
    #pragma unroll
    for (int n = 0; n < 4; ++n)
      ao[arow + n * 16 + l15] = f2b(o[n][r] * invq);
  }
}

// ---------------- head-average from u8 scratch ----------------
__global__ __launch_bounds__(256)
void k_avg(const unsigned char* __restrict__ pscr, const float* __restrict__ sums,
           float* __restrict__ avg, int b0, int plocal) {
  const int i = blockIdx.x, b = b0 + blockIdx.y;
  const int j0 = threadIdx.x * 8;
  float acc[8] = {};
  #pragma unroll
  for (int hh = 0; hh < 8; ++hh) {
    float inv = sums[(size_t)(b * 8 + hh) * TT + i];
    int pi = plocal ? hh : (b * 8 + hh);
    uint2 p = *(const uint2*)(pscr + ((size_t)pi * TT + i) * TT + j0);
    #pragma unroll
    for (int jj = 0; jj < 4; ++jj) {
      acc[jj]     += (float)((p.x >> (8 * jj)) & 255u) * inv;
      acc[4 + jj] += (float)((p.y >> (8 * jj)) & 255u) * inv;
    }
  }
  const float sc = 1.f / (24.f * 8.f);
  float4 q0 = {acc[0] * sc, acc[1] * sc, acc[2] * sc, acc[3] * sc};
  float4 q1 = {acc[4] * sc, acc[5] * sc, acc[6] * sc, acc[7] * sc};
  float* op = avg + ((size_t)(b * TT + i)) * TT + j0;
  *(float4*)op = q0;
  *(float4*)(op + 4) = q1;
}

// ---------------- two-pass attention with in-LDS avg (fallback only) ----------------
#define KS 32
#define NSTEP (TT / KS)

__device__ __forceinline__ void loadK(const unsigned short* src, u16x8* kr) {
  int row = threadIdx.x >> 4, c0 = (threadIdx.x & 15) * 8;
  const unsigned short* p = src + row * 512 + c0;
  #pragma unroll
  for (int j = 0; j < 4; ++j) kr[j] = *(const u16x8*)(p + j * 128);
}
__device__ __forceinline__ void writeK(unsigned short* Kt, const u16x8* kr) {
  int row = threadIdx.x >> 4, c0 = (threadIdx.x & 15) * 8, sw = (row & 7) << 3;
  #pragma unroll
  for (int j = 0; j < 4; ++j)
    *(u16x8*)(Kt + row * 512 + ((c0 + j * 128) ^ sw)) = kr[j];
}
__device__ __forceinline__ void loadV(const unsigned short* vt_b, int s0, u16x8* vr) {
  const unsigned short* p = vt_b + (size_t)threadIdx.x * TT + s0;
  #pragma unroll
  for (int j = 0; j < 4; ++j) vr[j] = *(const u16x8*)(p + j * 8);
}
__device__ __forceinline__ void writeV(unsigned short* Vt, const u16x8* vr) {
  int row = threadIdx.x, sw = ((row >> 1) & 3) << 3;
  #pragma unroll
  for (int j = 0; j < 4; ++j)
    *(u16x8*)(Vt + row * 32 + ((j * 8) ^ sw)) = vr[j];
}

__global__ __launch_bounds__(512)
void k_attn(const unsigned short* __restrict__ q, const unsigned short* __restrict__ kk,
            const unsigned short* __restrict__ vt, unsigned short* __restrict__ ao,
            float* __restrict__ avg) {
  __shared__ __align__(16) unsigned short Kt[2][KS * 512];
  __shared__ __align__(16) unsigned short Vt[2][512 * KS];
  __shared__ __align__(16) unsigned short Pb[2][NH][16][40];
  const int tid  = threadIdx.x;
  const int lane = tid & 63;
  const int w    = tid >> 6;
  const int l15  = lane & 15;
  const int g    = lane >> 4;
  const int qt   = blockIdx.x;
  const int b    = blockIdx.y;

  const unsigned short* kbase = kk + (size_t)(b * TT) * DMODEL;
  const unsigned short* vbase = vt + (size_t)b * DMODEL * TT;

  const size_t qoff = (size_t)(b * TT + qt * 16 + l15) * DMODEL + w * HD + g * 8;
  const bf16x8 aq0 = *(const bf16x8*)(q + qoff);
  const bf16x8 aq1 = *(const bf16x8*)(q + qoff + 32);

  u16x8 kr[4], vr[4];

  float ssum[4] = {0.f, 0.f, 0.f, 0.f};
  loadK(kbase, kr);
  writeK(Kt[0], kr);
  __syncthreads();
  for (int s = 0; s < NSTEP; ++s) {
    const int cur = s & 1;
    if (s < NSTEP - 1) loadK(kbase + (size_t)(s + 1) * KS * 512, kr);
    f32x4 sf[2] = {};
    #pragma unroll
    for (int n = 0; n < 2; ++n) {
      const int row = n * 16 + l15, sw = (row & 7) << 3;
      const unsigned short* kp = Kt[cur] + row * 512;
      bf16x8 b0 = *(const bf16x8*)(kp + ((w * 64 + g * 8) ^ sw));
      bf16x8 b1 = *(const bf16x8*)(kp + ((w * 64 + 32 + g * 8) ^ sw));
      sf[n] = mfma16(aq0, b0, sf[n]);
      sf[n] = mfma16(aq1, b1, sf[n]);
    }
    #pragma unroll
    for (int r = 0; r < 4; ++r)
      ssum[r] += __expf(sf[0][r] * 0.125f) + __expf(sf[1][r] * 0.125f);
    if (s < NSTEP - 1) writeK(Kt[cur ^ 1], kr);
    __syncthreads();
  }
  float inv_s[4];
  #pragma unroll
  for (int r = 0; r < 4; ++r) {
    float v = ssum[r];
    v += __shfl_xor(v, 1);
    v += __shfl_xor(v, 2);
    v += __shfl_xor(v, 4);
    v += __shfl_xor(v, 8);
    inv_s[r] = 1.f / v;
  }

  f32x4 o[4] = {};
  loadK(kbase, kr);
  loadV(vbase, 0, vr);
  writeK(Kt[0], kr);
  writeV(Vt[0], vr);
  __syncthreads();
  for (int s = 0; s < NSTEP; ++s) {
    const int cur = s & 1;
    if (s < NSTEP - 1) {
      loadK(kbase + (size_t)(s + 1) * KS * 512, kr);
      loadV(vbase, (s + 1) * KS, vr);
    }
    f32x4 sf[2] = {};
    #pragma unroll
    for (int n = 0; n < 2; ++n) {
      const int row = n * 16 + l15, sw = (row & 7) << 3;
      const unsigned short* kp = Kt[cur] + row * 512;
      bf16x8 b0 = *(const bf16x8*)(kp + ((w * 64 + g * 8) ^ sw));
      bf16x8 b1 = *(const bf16x8*)(kp + ((w * 64 + 32 + g * 8) ^ sw));
      sf[n] = mfma16(aq0, b0, sf[n]);
      sf[n] = mfma16(aq1, b1, sf[n]);
    }
    #pragma unroll
    for (int n = 0; n < 2; ++n)
      #pragma unroll
      for (int r = 0; r < 4; ++r)
        Pb[cur][w][g * 4 + r][n * 16 + l15] = f2b(__expf(sf[n][r] * 0.125f) * inv_s[r]);
    __syncthreads();

    bf16x8 pa = *(const bf16x8*)&Pb[cur][w][l15][g * 8];
    #pragma unroll
    for (int n = 0; n < 4; ++n) {
      const int row = w * 64 + n * 16 + l15;
      bf16x8 bv = *(const bf16x8*)(Vt[cur] + row * 32 + ((g * 8) ^ (((row >> 1) & 3) << 3)));
      o[n] = mfma16(pa, bv, o[n]);
    }
    {
      int i = tid >> 5, j = tid & 31;
      float sm = 0.f;
      #pragma unroll
      for (int hh = 0; hh < NH; ++hh) sm += b2f(Pb[cur][hh][i][j]);
      avg[(size_t)(b * TT + qt * 16 + i) * TT + s * KS + j] = sm * 0.125f;
    }
    if (s < NSTEP - 1) {
      writeK(Kt[cur ^ 1], kr);
      writeV(Vt[cur ^ 1], vr);
    }
    __syncthreads();
  }

  #pragma unroll
  for (int n = 0; n < 4; ++n)
    #pragma unroll
    for (int r = 0; r < 4; ++r)
      ao[(size_t)(b * TT + qt * 16 + g * 4 + r) * DMODEL + w * HD + n * 16 + l15] = f2b(o[n][r]);
}

// ---------------- final mean over T ----------------
__global__ void k_mean(const float* __restrict__ hf, float* __restrict__ out) {
  int c = blockIdx.x * 256 + threadIdx.x;
  int b = blockIdx.y;
  int t0 = blockIdx.z * 128;
  float s = 0.f;
  for (int t = 0; t < 128; ++t)
    s += hf[(size_t)(b * TT + t0 + t) * DMODEL + c];
  atomicAdd(&out[b * DMODEL + c], s * (1.f / TT));
}

extern "C" void kernel_launch(void* const* d_in, const int* in_sizes, int n_in,
                              void* d_out, int out_size, void* d_ws, size_t ws_size,
                              hipStream_t stream) {
  const int*   x    = (const int*)d_in[0];
  const float* emb  = (const float*)d_in[1];
  const float* pos  = (const float*)d_in[2];
  const float* Wq   = (const float*)d_in[3];
  const float* bq   = (const float*)d_in[4];
  const float* Wk   = (const float*)d_in[5];
  const float* bk   = (const float*)d_in[6];
  const float* Wv   = (const float*)d_in[7];
  const float* bv   = (const float*)d_in[8];
  const float* Wo   = (const float*)d_in[9];
  const float* bo   = (const float*)d_in[10];
  const float* W1   = (const float*)d_in[11];
  const float* b1   = (const float*)d_in[12];
  const float* W2   = (const float*)d_in[13];
  const float* b2   = (const float*)d_in[14];
  const float* ln1g = (const float*)d_in[15];
  const float* ln1b = (const float*)d_in[16];
  const float* ln2g = (const float*)d_in[17];
  const float* ln2b = (const float*)d_in[18];
  const float* lnfg = (const float*)d_in[19];
  const float* lnfb = (const float*)d_in[20];

  char* w = (char*)d_ws;
  const size_t MB = 1024 * 1024;
  unsigned short* wqb = (unsigned short*)(w + 0 * MB);
  unsigned short* wkb = (unsigned short*)(w + 2 * MB);
  unsigned short* wvb = (unsigned short*)(w + 4 * MB);
  unsigned short* wob = (unsigned short*)(w + 6 * MB);
  unsigned short* w1b = (unsigned short*)(w + 8 * MB);
  unsigned short* w2b = (unsigned short*)(w + 16 * MB);
  float*          h   = (float*)(w + 24 * MB);
  unsigned short* hn  = (unsigned short*)(w + 32 * MB);
  unsigned short* qb  = (unsigned short*)(w + 36 * MB);
  unsigned short* kb  = (unsigned short*)(w + 40 * MB);
  unsigned short* vtb = (unsigned short*)(w + 48 * MB);
  unsigned short* ab  = (unsigned short*)(w + 52 * MB);
  unsigned short* ff  = (unsigned short*)(w + 56 * MB);   // 16 MB
  float*          sums = (float*)(w + 72 * MB);           // 128 KB
  unsigned char*  pscr_ws = (unsigned char*)(w + 73 * MB);
  float*          hf  = (float*)(w + 36 * MB);            // reuse q space after layers

  k_f2b_all<<<dim3(4096, 6), 256, 0, stream>>>(Wq, Wk, Wv, Wo, W1, W2,
                                               wqb, wkb, wvb, wob, w1b, w2b);

  k_embed<<<BB * TT, 128, 0, stream>>>(x, emb, pos, h);

  float* attn_maps = (float*)d_out + 1024;
  const size_t RSZ = (size_t)BB * TT * TT;               // floats per map region (32 MiB)
  const size_t NEED_FULL = 73 * MB + 64 * MB;
  const size_t NEED_HALF = 73 * MB + 32 * MB;

  for (int l = 0; l < 4; ++l) {
    k_ln<1><<<BB * TT / 4, 256, 0, stream>>>(h, ln1g + l * DMODEL, ln1b + l * DMODEL, hn);
    dim3 gq(DMODEL / 128, BB * TT / 128, 3);
    k_gemm_qkv<<<gq, 256, 0, stream>>>(hn,
        wqb + (size_t)l * DMODEL * DMODEL, wkb + (size_t)l * DMODEL * DMODEL,
        wvb + (size_t)l * DMODEL * DMODEL,
        bq + l * DMODEL, bk + l * DMODEL, bv + l * DMODEL, qb, kb, vtb);

    float* maps_l = attn_maps + (size_t)l * RSZ;
    if (l <= 1) {
      unsigned char* ps = (unsigned char*)(attn_maps + (size_t)(l + 1) * RSZ);
      k_attn1<<<dim3(TT / 64, BB * NH), 256, 0, stream>>>(qb, kb, vtb, ab, ps, sums, 0, 0);
      k_avg<<<dim3(TT, BB), 256, 0, stream>>>(ps, sums, maps_l, 0, 0);
    } else if (l == 2) {
      unsigned char* ps = (unsigned char*)(attn_maps + (size_t)3 * RSZ);
      for (int b = 0; b < BB; ++b) {
        k_attn1<<<dim3(TT / 64, NH), 256, 0, stream>>>(qb, kb, vtb, ab, ps, sums, b * NH, 1);
        k_avg<<<dim3(TT, 1), 256, 0, stream>>>(ps, sums, maps_l, b, 1);
      }
    } else {
      if (ws_size >= NEED_FULL) {
        k_attn1<<<dim3(TT / 64, BB * NH), 256, 0, stream>>>(qb, kb, vtb, ab, pscr_ws, sums, 0, 0);
        k_avg<<<dim3(TT, BB), 256, 0, stream>>>(pscr_ws, sums, maps_l, 0, 0);
      } else if (ws_size >= NEED_HALF) {
        for (int b = 0; b < BB; ++b) {
          k_attn1<<<dim3(TT / 64, NH), 256, 0, stream>>>(qb, kb, vtb, ab, pscr_ws, sums, b * NH, 1);
          k_avg<<<dim3(TT, 1), 256, 0, stream>>>(pscr_ws, sums, maps_l, b, 1);
        }
      } else {
        k_attn<<<dim3(TT / 16, BB), 512, 0, stream>>>(qb, kb, vtb, ab, maps_l);
      }
    }

    k_gemm_bm64<0, 1, 0><<<dim3(DMODEL / 128, BB * TT / 64), 256, 0, stream>>>(ab,
        wob + (size_t)l * DMODEL * DMODEL, bo + l * DMODEL, h, nullptr, h, 4096, 512, 512);
    k_ln<1><<<BB * TT / 4, 256, 0, stream>>>(h, ln2g + l * DMODEL, ln2b + l * DMODEL, hn);
    k_gemm<1, 0, 1><<<dim3(DFF / 128, BB * TT / 128), 256, 0, stream>>>(hn,
        w1b + (size_t)l * DFF * DMODEL, b1 + l * DFF, nullptr, ff, nullptr, 4096, 2048, 512);
    k_gemm_bm64<0, 1, 0><<<dim3(DMODEL / 128, BB * TT / 64), 256, 0, stream>>>(ff,
        w2b + (size_t)l * DMODEL * DFF, b2 + l * DMODEL, h, nullptr, h, 4096, 512, 2048);
  }
  k_ln<0><<<BB * TT / 4, 256, 0, stream>>>(h, lnfg, lnfb, hf);
  hipMemsetAsync(d_out, 0, 1024 * sizeof(float), stream);
  k_mean<<<dim3(2, BB, 16), 256, 0, stream>>>(hf, (float*)d_out);
}